// Round 4
// baseline (366.564 us; speedup 1.0000x reference)
//
#include <hip/hip_runtime.h>
#include <hip/hip_bf16.h>

#define CL 2
#define CB 4
#define CT 1024
#define CD 256
#define CH 4
#define CM 1024
#define CHD (CH * CD)      // 1024
#define NROW (CB * CT)     // 4096

typedef unsigned short ushort_t;
typedef __attribute__((ext_vector_type(8))) short short8v;   // 8 bf16 (4 VGPR)
typedef __attribute__((ext_vector_type(4))) float float4v;   // MFMA C/D frag 16x16
typedef __attribute__((ext_vector_type(16))) float float16v; // MFMA C/D frag 32x32

#define LOG2E 1.44269504088896f

__device__ __forceinline__ float bf2f(unsigned short u) {
    return __uint_as_float(((unsigned int)u) << 16);
}
__device__ __forceinline__ unsigned short f2bf(float f) {
    unsigned int x = __float_as_uint(f);
    return (unsigned short)((x + 0x7fffu + ((x >> 16) & 1u)) >> 16);
}

// ---------------------------------------------------------------------------
// Input-dtype detection (2048 elems; fp32-underlying -> ~430 anomalies, bf16 0)
// ---------------------------------------------------------------------------
__global__ __launch_bounds__(256) void detect_kernel(
    const ushort_t* __restrict__ w, int n, int* __restrict__ flag)
{
    __shared__ int red[256];
    int c = 0;
    for (int i = threadIdx.x; i < n; i += 256) {
        float v = bf2f(w[i]);
        if (!(fabsf(v) <= 1e6f)) c++;
    }
    red[threadIdx.x] = c;
    __syncthreads();
    for (int s = 128; s > 0; s >>= 1) {
        if (threadIdx.x < s) red[threadIdx.x] += red[threadIdx.x + s];
        __syncthreads();
    }
    if (threadIdx.x == 0) flag[0] = (red[0] < 8) ? 1 : 0;
}

// ---------------------------------------------------------------------------
// Prepass transpose: Wq/Wk/Wv/W1 (all [L][256][1024]) -> bf16 transposed.
// Grid (32, 8, 8): z = which*2 + l.
// ---------------------------------------------------------------------------
__global__ __launch_bounds__(256) void tconv_all(
    const void* __restrict__ Wq, const void* __restrict__ Wk,
    const void* __restrict__ Wv, const void* __restrict__ W1,
    ushort_t* __restrict__ wqkvT, ushort_t* __restrict__ w1T,
    const int* __restrict__ flagp)
{
    const int fbf = *flagp;
    const int z = blockIdx.z;
    const int which = z >> 1, l = z & 1;
    const void* in = (which == 0) ? Wq : (which == 1) ? Wk
                   : (which == 2) ? Wv : W1;
    ushort_t* out = (which < 3)
        ? wqkvT + (long)l * 3072 * 256 + (long)which * 1024 * 256
        : w1T + (long)l * 1024 * 256;
    const long zi = (long)l * 262144;

    __shared__ float tile[32][33];
    const int r0 = blockIdx.y * 32;
    const int c0 = blockIdx.x * 32;
    const int tx = threadIdx.x & 31;
    const int ty = threadIdx.x >> 5;
#pragma unroll
    for (int i = 0; i < 32; i += 8) {
        const long idx = zi + (long)(r0 + ty + i) * 1024 + c0 + tx;
        tile[ty + i][tx] = fbf ? bf2f(((const ushort_t*)in)[idx])
                               : ((const float*)in)[idx];
    }
    __syncthreads();
#pragma unroll
    for (int i = 0; i < 32; i += 8)
        out[(long)(c0 + ty + i) * 256 + r0 + tx] = f2bf(tile[tx][ty + i]);
}

// ---------------------------------------------------------------------------
// Merged QKV projection + Wo/W2 transpose (one dispatch).
// Blocks 0..767: qkv 128x128 tiles. Blocks 768..1279: tconv2.
// ---------------------------------------------------------------------------
__global__ __launch_bounds__(256) void qkv_tconv(
    const ushort_t* __restrict__ A, const ushort_t* __restrict__ B,
    const void* __restrict__ bq, const void* __restrict__ bk,
    const void* __restrict__ bv, ushort_t* __restrict__ qk,
    ushort_t* __restrict__ vT,
    const void* __restrict__ Wo, const void* __restrict__ W2,
    ushort_t* __restrict__ wscr,
    long boff, long ioff, const int* __restrict__ flagp)
{
    __shared__ __align__(16) ushort_t As[128 * 40];
    __shared__ __align__(16) ushort_t Bs[128 * 40];
    __shared__ float tile[32][33];

    const int fbf = *flagp;
    const int bx = blockIdx.x;
    const int tid = threadIdx.x;

    if (bx >= 768) {
        // ---- tconv2 part ----
        const int t = bx - 768;          // 0..511
        const int zx = t & 7;            // col-tile (256/32)
        const int zy = (t >> 3) & 31;    // row-tile (1024/32)
        const int zz = t >> 8;           // 0 = Wo, 1 = W2
        const void* in = zz ? W2 : Wo;
        ushort_t* out = wscr + (long)zz * 262144;
        const int r0 = zy * 32;
        const int c0 = zx * 32;
        const int tx = tid & 31;
        const int ty = tid >> 5;
#pragma unroll
        for (int i = 0; i < 32; i += 8) {
            const long idx = ioff + (long)(r0 + ty + i) * 256 + c0 + tx;
            tile[ty + i][tx] = fbf ? bf2f(((const ushort_t*)in)[idx])
                                   : ((const float*)in)[idx];
        }
        __syncthreads();
#pragma unroll
        for (int i = 0; i < 32; i += 8)
            out[(long)(c0 + ty + i) * 1024 + r0 + tx] = f2bf(tile[tx][ty + i]);
        return;
    }

    // ---- qkv part ----
    const int nt = bx % 24;
    const int mt = bx / 24;
    const long m0 = (long)mt * 128;
    const long n0 = (long)nt * 128;

    const int wave = tid >> 6;
    const int lane = tid & 63;
    const int quad = lane >> 4;
    const int lrow = lane & 15;
    const int wm = (wave >> 1) * 64;
    const int wn = (wave & 1) * 64;

    float4v acc[4][4];
#pragma unroll
    for (int i = 0; i < 4; ++i)
#pragma unroll
        for (int j = 0; j < 4; ++j)
            acc[i][j] = (float4v){0.f, 0.f, 0.f, 0.f};

    for (int k0 = 0; k0 < 256; k0 += 32) {
        __syncthreads();
#pragma unroll
        for (int p = 0; p < 2; ++p) {
            const int c = p * 256 + tid;
            const int row = c >> 2;
            const int kk = (c & 3) << 3;
            *reinterpret_cast<short8v*>(&As[row * 40 + kk]) =
                *reinterpret_cast<const short8v*>(&A[(m0 + row) * 256 + k0 + kk]);
            *reinterpret_cast<short8v*>(&Bs[row * 40 + kk]) =
                *reinterpret_cast<const short8v*>(&B[(n0 + row) * 256 + k0 + kk]);
        }
        __syncthreads();

        short8v af[4], bfv[4];
#pragma unroll
        for (int i = 0; i < 4; ++i) {
            af[i]  = *reinterpret_cast<const short8v*>(&As[(wm + i * 16 + lrow) * 40 + quad * 8]);
            bfv[i] = *reinterpret_cast<const short8v*>(&Bs[(wn + i * 16 + lrow) * 40 + quad * 8]);
        }
#pragma unroll
        for (int mi = 0; mi < 4; ++mi)
#pragma unroll
            for (int ni = 0; ni < 4; ++ni)
                acc[mi][ni] = __builtin_amdgcn_mfma_f32_16x16x32_bf16(
                    af[mi], bfv[ni], acc[mi][ni], 0, 0, 0);
    }

#pragma unroll
    for (int mi = 0; mi < 4; ++mi) {
#pragma unroll
        for (int ni = 0; ni < 4; ++ni) {
            const long col = n0 + wn + ni * 16 + lrow;
            const long row0 = m0 + wm + mi * 16 + quad * 4;
            const void* bp;
            long bn;
            if (col < 1024)      { bp = bq; bn = col; }
            else if (col < 2048) { bp = bk; bn = col - 1024; }
            else                 { bp = bv; bn = col - 2048; }
            const float bias = fbf ? bf2f(((const ushort_t*)bp)[boff + bn])
                                   : ((const float*)bp)[boff + bn];
            if (col < 2048) {
#pragma unroll
                for (int r = 0; r < 4; ++r)
                    qk[(row0 + r) * 2048 + col] = f2bf(acc[mi][ni][r] + bias);
            } else {
                const long d = col - 2048;
                const long addr = ((row0 >> 10) << 2) * 262144 + d * 1024 + (row0 & 1023);
                ushort4 u;
                u.x = f2bf(acc[mi][ni][0] + bias);
                u.y = f2bf(acc[mi][ni][1] + bias);
                u.z = f2bf(acc[mi][ni][2] + bias);
                u.w = f2bf(acc[mi][ni][3] + bias);
                *reinterpret_cast<ushort4*>(&vT[addr]) = u;
            }
        }
    }
}

// ---------------------------------------------------------------------------
// mgemm64s: 64x64-tile split-K GEMM -> fp32 partials. BK=64. Grid (N/64, M/64, 2).
// AMODE 1: attention-partial combine with scales HOISTED out of the k-loop.
// ---------------------------------------------------------------------------
template <int AMODE>
__global__ __launch_bounds__(256) void mgemm64s(
    const ushort_t* __restrict__ A, const ushort_t* __restrict__ Ap1,
    const float2* __restrict__ ml, const ushort_t* __restrict__ B,
    float* __restrict__ P, int K2, int lda, int ldb)
{
    const int z = blockIdx.z;
    const long m0 = (long)blockIdx.y * 64;
    const long n0 = (long)blockIdx.x * 64;
    const int k_beg = z * K2;

    __shared__ __align__(16) ushort_t As[64 * 72];
    __shared__ __align__(16) ushort_t Bs[64 * 72];

    const int tid = threadIdx.x;
    const int wave = tid >> 6;
    const int lane = tid & 63;
    const int quad = lane >> 4;
    const int lrow = lane & 15;
    const int wm = (wave >> 1) * 32;
    const int wn = (wave & 1) * 32;

    const int ar = tid >> 2;          // 0..63
    const int ak = (tid & 3) << 3;    // 0,8,16,24

    float s0h[2] = {0.f, 0.f}, s1h[2] = {0.f, 0.f};
    if constexpr (AMODE == 1) {
        const long m = m0 + ar;
        const int bhbase = ((int)(m >> 10) << 2);
        const int trow = (int)(m & 1023);
        const int h0 = k_beg >> 8;
#pragma unroll
        for (int i = 0; i < 2; ++i) {
            const int bh = bhbase + h0 + i;
            const float2 v0 = ml[bh * 1024 + trow];
            const float2 v1 = ml[(16 + bh) * 1024 + trow];
            const float mm = fmaxf(v0.x, v1.x);
            const float a0 = exp2f(v0.x - mm);
            const float a1 = exp2f(v1.x - mm);
            const float inv = 1.0f / (v0.y * a0 + v1.y * a1);
            s0h[i] = a0 * inv;
            s1h[i] = a1 * inv;
        }
    }

    float4v acc[2][2];
#pragma unroll
    for (int i = 0; i < 2; ++i)
#pragma unroll
        for (int j = 0; j < 2; ++j)
            acc[i][j] = (float4v){0.f, 0.f, 0.f, 0.f};

    for (int k0 = k_beg; k0 < k_beg + K2; k0 += 64) {
        __syncthreads();
#pragma unroll
        for (int p = 0; p < 2; ++p) {
            const int kc = p * 32 + ak;
            if constexpr (AMODE == 0) {
                *reinterpret_cast<short8v*>(&As[ar * 72 + kc]) =
                    *reinterpret_cast<const short8v*>(&A[(m0 + ar) * (long)lda + k0 + kc]);
            } else {
                const long m = m0 + ar;
                const int hi = ((k0 + kc) >> 8) - (k_beg >> 8);   // 0 or 1
                const float s0 = s0h[hi], s1 = s1h[hi];
                const ushort4 u0a = *reinterpret_cast<const ushort4*>(&A[m * 1024 + k0 + kc]);
                const ushort4 u0b = *reinterpret_cast<const ushort4*>(&A[m * 1024 + k0 + kc + 4]);
                const ushort4 u1a = *reinterpret_cast<const ushort4*>(&Ap1[m * 1024 + k0 + kc]);
                const ushort4 u1b = *reinterpret_cast<const ushort4*>(&Ap1[m * 1024 + k0 + kc + 4]);
                short8v t8;
                t8[0] = (short)f2bf(bf2f(u0a.x) * s0 + bf2f(u1a.x) * s1);
                t8[1] = (short)f2bf(bf2f(u0a.y) * s0 + bf2f(u1a.y) * s1);
                t8[2] = (short)f2bf(bf2f(u0a.z) * s0 + bf2f(u1a.z) * s1);
                t8[3] = (short)f2bf(bf2f(u0a.w) * s0 + bf2f(u1a.w) * s1);
                t8[4] = (short)f2bf(bf2f(u0b.x) * s0 + bf2f(u1b.x) * s1);
                t8[5] = (short)f2bf(bf2f(u0b.y) * s0 + bf2f(u1b.y) * s1);
                t8[6] = (short)f2bf(bf2f(u0b.z) * s0 + bf2f(u1b.z) * s1);
                t8[7] = (short)f2bf(bf2f(u0b.w) * s0 + bf2f(u1b.w) * s1);
                *reinterpret_cast<short8v*>(&As[ar * 72 + kc]) = t8;
            }
            *reinterpret_cast<short8v*>(&Bs[ar * 72 + kc]) =
                *reinterpret_cast<const short8v*>(&B[(n0 + ar) * (long)ldb + k0 + kc]);
        }
        __syncthreads();

#pragma unroll
        for (int kk = 0; kk < 2; ++kk) {
            short8v af[2], bfv[2];
#pragma unroll
            for (int i = 0; i < 2; ++i) {
                af[i]  = *reinterpret_cast<const short8v*>(
                    &As[(wm + i * 16 + lrow) * 72 + kk * 32 + quad * 8]);
                bfv[i] = *reinterpret_cast<const short8v*>(
                    &Bs[(wn + i * 16 + lrow) * 72 + kk * 32 + quad * 8]);
            }
#pragma unroll
            for (int mi = 0; mi < 2; ++mi)
#pragma unroll
                for (int ni = 0; ni < 2; ++ni)
                    acc[mi][ni] = __builtin_amdgcn_mfma_f32_16x16x32_bf16(
                        af[mi], bfv[ni], acc[mi][ni], 0, 0, 0);
        }
    }

    float* Pz = P + (long)z * NROW * CD;
#pragma unroll
    for (int mi = 0; mi < 2; ++mi)
#pragma unroll
        for (int ni = 0; ni < 2; ++ni) {
            const long col = n0 + wn + ni * 16 + lrow;
            const long row0 = m0 + wm + mi * 16 + quad * 4;
#pragma unroll
            for (int r = 0; r < 4; ++r)
                Pz[(row0 + r) * CD + col] = acc[mi][ni][r];
        }
}

// ---------------------------------------------------------------------------
// mgemm64b: 64x64-tile full-K GEMM (MLP1), BK=64, bias+relu, bf16 out.
// ---------------------------------------------------------------------------
template <int RELU>
__global__ __launch_bounds__(256) void mgemm64b(
    const ushort_t* __restrict__ A, const ushort_t* __restrict__ B,
    const void* __restrict__ bias, ushort_t* __restrict__ C,
    int K, int lda, int ldb, int ldc, long boff,
    const int* __restrict__ flagp)
{
    const long m0 = (long)blockIdx.y * 64;
    const long n0 = (long)blockIdx.x * 64;

    __shared__ __align__(16) ushort_t As[64 * 72];
    __shared__ __align__(16) ushort_t Bs[64 * 72];

    const int tid = threadIdx.x;
    const int wave = tid >> 6;
    const int lane = tid & 63;
    const int quad = lane >> 4;
    const int lrow = lane & 15;
    const int wm = (wave >> 1) * 32;
    const int wn = (wave & 1) * 32;

    const int ar = tid >> 2;
    const int ak = (tid & 3) << 3;

    float4v acc[2][2];
#pragma unroll
    for (int i = 0; i < 2; ++i)
#pragma unroll
        for (int j = 0; j < 2; ++j)
            acc[i][j] = (float4v){0.f, 0.f, 0.f, 0.f};

    for (int k0 = 0; k0 < K; k0 += 64) {
        __syncthreads();
#pragma unroll
        for (int p = 0; p < 2; ++p) {
            const int kc = p * 32 + ak;
            *reinterpret_cast<short8v*>(&As[ar * 72 + kc]) =
                *reinterpret_cast<const short8v*>(&A[(m0 + ar) * (long)lda + k0 + kc]);
            *reinterpret_cast<short8v*>(&Bs[ar * 72 + kc]) =
                *reinterpret_cast<const short8v*>(&B[(n0 + ar) * (long)ldb + k0 + kc]);
        }
        __syncthreads();

#pragma unroll
        for (int kk = 0; kk < 2; ++kk) {
            short8v af[2], bfv[2];
#pragma unroll
            for (int i = 0; i < 2; ++i) {
                af[i]  = *reinterpret_cast<const short8v*>(
                    &As[(wm + i * 16 + lrow) * 72 + kk * 32 + quad * 8]);
                bfv[i] = *reinterpret_cast<const short8v*>(
                    &Bs[(wn + i * 16 + lrow) * 72 + kk * 32 + quad * 8]);
            }
#pragma unroll
            for (int mi = 0; mi < 2; ++mi)
#pragma unroll
                for (int ni = 0; ni < 2; ++ni)
                    acc[mi][ni] = __builtin_amdgcn_mfma_f32_16x16x32_bf16(
                        af[mi], bfv[ni], acc[mi][ni], 0, 0, 0);
        }
    }

    const int fbf = *flagp;
#pragma unroll
    for (int mi = 0; mi < 2; ++mi)
#pragma unroll
        for (int ni = 0; ni < 2; ++ni) {
            const long col = n0 + wn + ni * 16 + lrow;
            const long row0 = m0 + wm + mi * 16 + quad * 4;
            const float bv = fbf ? bf2f(((const ushort_t*)bias)[boff + col])
                                 : ((const float*)bias)[boff + col];
#pragma unroll
            for (int r = 0; r < 4; ++r) {
                float v = acc[mi][ni][r] + bv;
                if (RELU) v = fmaxf(v, 0.f);
                C[(row0 + r) * (long)ldc + col] = f2bf(v);
            }
        }
}

// ---------------------------------------------------------------------------
// Flash attention v9: v8 32x32 structure + 8-wave blocks for 2 waves/SIMD.
//  - 256 blocks x 512 threads. Waves 0..3: four 32-row q-subtiles on kv-half
//    A (keys ck*512 .. +255); waves 4..7: SAME q-subtiles on kv-half B
//    (+256 .. +511). 1 block/CU, 8 waves/CU = 2 waves/SIMD (v8's failure was
//    1 wave/SIMD: zero TLP, OccupancyPercent 10.7, MfmaUtil 8.8).
//  - LDS: ping-pong x 2 halves x (16K Ks + 20K Vs) = 144 KB <= 160.
//  - End-of-block pair-combine (w, w+4) via LDS (K/V space dead by then):
//    m* = max(m0,m1), O = O0*2^(m0-m*) + O1*2^(m1-m*), l likewise. Writes
//    op0/op1 + ml exactly as v8 -> downstream AMODE1 combine unchanged.
//  - Defer-max threshold 8.0 (T13): fewer 128-fmul O-rescales.
//  - K LDS XOR-swizzled (proven v8: bank conflicts 5.6M -> 0.5M).
//  - __launch_bounds__(512,2) forces VGPR <= 256 (8 waves must co-reside).
// ---------------------------------------------------------------------------
__global__ __launch_bounds__(512, 2) void flash_attn(
    const ushort_t* __restrict__ qk, const ushort_t* __restrict__ vT,
    ushort_t* __restrict__ op0, ushort_t* __restrict__ op1,
    float2* __restrict__ ml)
{
    const int bx = blockIdx.x;
    const int bh = bx & 15;           // b*4 + h
    const int qg = (bx >> 4) & 7;     // 128-row q-group
    const int ck = bx >> 7;           // key-chunk 0/1
    const int bb = bh >> 2, h = bh & 3;

    // [buf][half] K: 32x256 swizzled at  (buf*2+half)*8192
    // [buf][half] V: 256x40 padded at 32768 + (buf*2+half)*10240
    // epilogue reuse: xO = 4 x 8192 floats (128 KB), xml at byte 131072.
    __shared__ __align__(16) ushort_t smem[73728];   // 144 KB

    const int tid = threadIdx.x;      // 0..511
    const int wave = tid >> 6;        // 0..7
    const int lane = tid & 63;
    const int col = lane & 31;
    const int hi = lane >> 5;
    const int hi8 = hi << 3;

    const int qsub = wave & 3;        // q-subtile within the 128-row group
    const int hf = wave >> 2;         // kv-half this wave consumes

    const long qrow0w = (long)bb * CT + qg * 128 + qsub * 32;
    const int qcol = h * 256;
    const int kcol = 1024 + h * 256;
    const long vbase = (long)bh * 256 * 1024;
    const float SC = 0.0625f * LOG2E;

    // staging: threads 0-255 stage half 0, threads 256-511 stage half 1
    const int sh = tid >> 8;
    const int st = tid & 255;
    const int kr_ = st >> 5;           // 0..7
    const int kc_ = (st & 31) << 3;    // 0..248
    const int vr_ = st >> 2;           // 0..63
    const int vc_ = (st & 3) << 3;     // 0..24
    const int t0s = ck * 512 + sh * 256;   // staging key base (this thread)
    ushort_t* KsS = smem + sh * 8192;              // + buf*16384
    ushort_t* VsS = smem + 32768 + sh * 10240;     // + buf*20480

    short8v kreg[4], vreg[4];
#pragma unroll
    for (int i = 0; i < 4; ++i) {
        kreg[i] = *reinterpret_cast<const short8v*>(
            &qk[((long)bb * CT + t0s + i * 8 + kr_) * 2048 + kcol + kc_]);
        vreg[i] = *reinterpret_cast<const short8v*>(
            &vT[vbase + (long)(i * 64 + vr_) * 1024 + t0s + vc_]);
    }

    // Q B-frags: lane holds Q[qrow0w + col][s*16 + hi*8 .. +7]
    short8v qf[16];
#pragma unroll
    for (int s = 0; s < 16; ++s)
        qf[s] = *reinterpret_cast<const short8v*>(
            &qk[(qrow0w + col) * 2048 + qcol + s * 16 + hi8]);

    float mrun = -1e30f, lrun = 0.f;
    float16v oacc[8];
#pragma unroll
    for (int i = 0; i < 8; ++i)
#pragma unroll
        for (int j = 0; j < 16; ++j) oacc[i][j] = 0.f;

    // stage tile 0 into buf 0 (K swizzled: phys 16B-chunk = logical ^ row)
#pragma unroll
    for (int i = 0; i < 4; ++i) {
        const int kr = i * 8 + kr_;
        *reinterpret_cast<short8v*>(&KsS[kr * 256 + (((st & 31) ^ kr) << 3)]) = kreg[i];
        *reinterpret_cast<short8v*>(&VsS[(i * 64 + vr_) * 40 + vc_]) = vreg[i];
    }
    __syncthreads();

    // compute-side bases for this wave's half
    ushort_t* KsW = smem + hf * 8192;              // + cur*16384
    ushort_t* VsW = smem + 32768 + hf * 10240;     // + cur*20480
    const int krowbase = col * 256;
    const int kxor = col << 4;

    for (int it = 0; it < 8; ++it) {
        const int cur = it & 1;

        // prefetch tile it+1 into registers (consumed after compute)
        if (it < 7) {
            const int tn = t0s + (it + 1) * 32;
#pragma unroll
            for (int i = 0; i < 4; ++i) {
                kreg[i] = *reinterpret_cast<const short8v*>(
                    &qk[((long)bb * CT + tn + i * 8 + kr_) * 2048 + kcol + kc_]);
                vreg[i] = *reinterpret_cast<const short8v*>(
                    &vT[vbase + (long)(i * 64 + vr_) * 1024 + tn + vc_]);
            }
        }

        // ---- QK^T -> S^T[t][q]  (2-way split acc)
        const ushort_t* Kc = KsW + cur * 16384;
        float16v sa, sb;
#pragma unroll
        for (int j = 0; j < 16; ++j) { sa[j] = 0.f; sb[j] = 0.f; }
        __builtin_amdgcn_s_setprio(1);
#pragma unroll
        for (int s = 0; s < 16; s += 2) {
            const int o0 = ((s * 32 + hi * 16) ^ kxor) >> 1;
            const int o1 = (((s + 1) * 32 + hi * 16) ^ kxor) >> 1;
            const short8v k0 = *reinterpret_cast<const short8v*>(&Kc[krowbase + o0]);
            const short8v k1 = *reinterpret_cast<const short8v*>(&Kc[krowbase + o1]);
            sa = __builtin_amdgcn_mfma_f32_32x32x16_bf16(k0, qf[s], sa, 0, 0, 0);
            sb = __builtin_amdgcn_mfma_f32_32x32x16_bf16(k1, qf[s + 1], sb, 0, 0, 0);
        }
        __builtin_amdgcn_s_setprio(0);

        float sv[16];
#pragma unroll
        for (int j = 0; j < 16; ++j) sv[j] = (sa[j] + sb[j]) * SC;

        // ---- row max (q = lane&31; lane l^32 holds the other 16 k's)
        float mx = sv[0];
#pragma unroll
        for (int j = 1; j < 16; ++j) mx = fmaxf(mx, sv[j]);
        mx = fmaxf(mx, __shfl_xor(mx, 32));

        if (__ballot(mx > mrun + 8.0f) != 0ull) {   // T13 defer-max THR=8
            const float mnew = fmaxf(mrun, mx);
            const float alpha = exp2f(mrun - mnew);
            mrun = mnew;
            lrun *= alpha;
            float ar[16];
#pragma unroll
            for (int r = 0; r < 16; ++r)
                ar[r] = __shfl(alpha, (r & 3) + 8 * (r >> 2) + (hi << 2));
#pragma unroll
            for (int dt = 0; dt < 8; ++dt)
#pragma unroll
                for (int r = 0; r < 16; ++r)
                    oacc[dt][r] *= ar[r];
        }

        // ---- P = exp2(S - m), l-sum
        float p[16];
        float s = 0.f;
#pragma unroll
        for (int j = 0; j < 16; ++j) { p[j] = exp2f(sv[j] - mrun); s += p[j]; }
        s += __shfl_xor(s, 32);
        lrun += s;

        // ---- pack P to bf16 PV A-frags (half-exchange via shfl_xor 32)
        const unsigned c01 = (unsigned)f2bf(p[0])  | ((unsigned)f2bf(p[1])  << 16);
        const unsigned c23 = (unsigned)f2bf(p[2])  | ((unsigned)f2bf(p[3])  << 16);
        const unsigned c45 = (unsigned)f2bf(p[4])  | ((unsigned)f2bf(p[5])  << 16);
        const unsigned c67 = (unsigned)f2bf(p[6])  | ((unsigned)f2bf(p[7])  << 16);
        const unsigned d01 = (unsigned)f2bf(p[8])  | ((unsigned)f2bf(p[9])  << 16);
        const unsigned d23 = (unsigned)f2bf(p[10]) | ((unsigned)f2bf(p[11]) << 16);
        const unsigned d45 = (unsigned)f2bf(p[12]) | ((unsigned)f2bf(p[13]) << 16);
        const unsigned d67 = (unsigned)f2bf(p[14]) | ((unsigned)f2bf(p[15]) << 16);
        const unsigned x01 = __shfl_xor(c01, 32);
        const unsigned x23 = __shfl_xor(c23, 32);
        const unsigned x45 = __shfl_xor(c45, 32);
        const unsigned x67 = __shfl_xor(c67, 32);
        const unsigned y01 = __shfl_xor(d01, 32);
        const unsigned y23 = __shfl_xor(d23, 32);
        const unsigned y45 = __shfl_xor(d45, 32);
        const unsigned y67 = __shfl_xor(d67, 32);
        union { unsigned u[4]; short8v v; } pf0, pf1;
        pf0.u[0] = hi ? x45 : c01;
        pf0.u[1] = hi ? x67 : c23;
        pf0.u[2] = hi ? c45 : x01;
        pf0.u[3] = hi ? c67 : x23;
        pf1.u[0] = hi ? y45 : d01;
        pf1.u[1] = hi ? y67 : d23;
        pf1.u[2] = hi ? d45 : y01;
        pf1.u[3] = hi ? d67 : y23;

        // ---- PV: O[q][d] += P * V   (8 independent d-tiles)
        const ushort_t* Vc = VsW + cur * 20480;
        __builtin_amdgcn_s_setprio(1);
#pragma unroll
        for (int dt = 0; dt < 8; ++dt) {
            const int vb = (dt * 32 + col) * 40 + hi8;
            const short8v v0 = *reinterpret_cast<const short8v*>(&Vc[vb]);
            const short8v v1 = *reinterpret_cast<const short8v*>(&Vc[vb + 16]);
            oacc[dt] = __builtin_amdgcn_mfma_f32_32x32x16_bf16(pf0.v, v0, oacc[dt], 0, 0, 0);
            oacc[dt] = __builtin_amdgcn_mfma_f32_32x32x16_bf16(pf1.v, v1, oacc[dt], 0, 0, 0);
        }
        __builtin_amdgcn_s_setprio(0);

        // ---- write prefetched tile into the other buffer; one barrier/tile
        if (it < 7) {
            const int nb = cur ^ 1;
#pragma unroll
            for (int i = 0; i < 4; ++i) {
                const int kr = i * 8 + kr_;
                *reinterpret_cast<short8v*>(
                    &KsS[nb * 16384 + kr * 256 + (((st & 31) ^ kr) << 3)]) = kreg[i];
                *reinterpret_cast<short8v*>(
                    &VsS[nb * 20480 + (i * 64 + vr_) * 40 + vc_]) = vreg[i];
            }
            __syncthreads();
        }
    }

    // ---- in-block combine of the two kv-halves (pairs w <-> w+4) ----
    __syncthreads();                               // K/V LDS now dead
    float* xO = (float*)smem;                      // [qsub][dt*16+r][hi*32+col]
    float2* xml = (float2*)((char*)smem + 131072); // [qsub*32 + q]

    if (hf == 1) {
#pragma unroll
        for (int dt = 0; dt < 8; ++dt)
#pragma unroll
            for (int r = 0; r < 16; ++r)
                xO[qsub * 8192 + (dt * 16 + r) * 64 + (hi << 5) + col] = oacc[dt][r];
        if (hi == 0)
            xml[qsub * 32 + col] = make_float2(mrun, lrun);
    }
    __syncthreads();

    if (hf == 0) {
        const float2 o2 = xml[qsub * 32 + col];
        const float mstar = fmaxf(mrun, o2.x);
        const float a0 = exp2f(mrun - mstar);
        const float a2 = exp2f(o2.x - mstar);
        const float lnew = lrun * a0 + o2.y * a2;
        float ar0[16], ar2[16];
#pragma unroll
        for (int r = 0; r < 16; ++r) {
            const int li = (r & 3) + 8 * (r >> 2) + (hi << 2);
            ar0[r] = __shfl(a0, li);
            ar2[r] = __shfl(a2, li);
        }
        if (lane < 32) {
            const int trow = (int)((qrow0w + lane) & 1023);
            ml[((ck << 4) + bh) * 1024 + trow] = make_float2(mstar, lnew);
        }
        ushort_t* op = ck ? op1 : op0;
#pragma unroll
        for (int dt = 0; dt < 8; ++dt)
#pragma unroll
            for (int r = 0; r < 16; ++r) {
                const int row = (r & 3) + 8 * (r >> 2) + (hi << 2);
                const float of = oacc[dt][r] * ar0[r]
                    + xO[qsub * 8192 + (dt * 16 + r) * 64 + (hi << 5) + col] * ar2[r];
                op[(qrow0w + row) * 1024 + (h << 8) + dt * 32 + col] = f2bf(of);
            }
    }
}

// ---------------------------------------------------------------------------
// ln_p: x = P0[row]+P1[row] + gbias + res; y = LN(x)*s + b.
// FINAL=1 writes d_out in flag dtype.
// ---------------------------------------------------------------------------
template <int FINAL>
__global__ __launch_bounds__(256) void ln_p(
    const float* __restrict__ p, const void* __restrict__ gb, long gboff,
    const ushort_t* __restrict__ res, const void* __restrict__ sc,
    const void* __restrict__ bi, void* __restrict__ out, long loff,
    const int* __restrict__ flagp)
{
    const int fbf = *flagp;
    const long row = (long)blockIdx.x * CD;
    const int t = threadIdx.x;
    const float gbv = fbf ? bf2f(((const ushort_t*)gb)[gboff + t])
                          : ((const float*)gb)[gboff + t];
    const float x = p[row + t] + p[(long)NROW * CD + row + t] + gbv + bf2f(res[row + t]);

    __shared__ float r1[256];
    __shared__ float r2[256];
    r1[t] = x;
    r2[t] = x * x;
    __syncthreads();
    for (int s = 128; s > 0; s >>= 1) {
        if (t < s) { r1[t] += r1[t + s]; r2[t] += r2[t + s]; }
        __syncthreads();
    }
    const float mean = r1[0] * (1.0f / CD);
    const float var = r2[0] * (1.0f / CD) - mean * mean;
    const float rstd = rsqrtf(var + 1e-5f);
    const float s_v = fbf ? bf2f(((const ushort_t*)sc)[loff + t]) : ((const float*)sc)[loff + t];
    const float b_v = fbf ? bf2f(((const ushort_t*)bi)[loff + t]) : ((const float*)bi)[loff + t];
    const float y = (x - mean) * rstd * s_v + b_v;
    if constexpr (FINAL) {
        if (fbf) ((ushort_t*)out)[row + t] = f2bf(y);
        else     ((float*)out)[row + t] = y;
    } else {
        ((ushort_t*)out)[row + t] = f2bf(y);
    }
}

__global__ __launch_bounds__(256) void in_convert(
    const void* __restrict__ in, ushort_t* __restrict__ x,
    const int* __restrict__ flagp)
{
    const int fbf = *flagp;
    const long i = ((long)blockIdx.x * 256 + threadIdx.x) << 2;
    if (fbf) {
        *reinterpret_cast<ushort4*>(x + i) =
            *reinterpret_cast<const ushort4*>((const ushort_t*)in + i);
    } else {
        float4 f = *reinterpret_cast<const float4*>((const float*)in + i);
        ushort4 u;
        u.x = f2bf(f.x); u.y = f2bf(f.y); u.z = f2bf(f.z); u.w = f2bf(f.w);
        *reinterpret_cast<ushort4*>(x + i) = u;
    }
}

// ---------------------------------------------------------------------------
// Orchestration. ws = 47.25 MB + 256 B. Dispatches: 3 + 7/layer x 2 = 17.
// ---------------------------------------------------------------------------
extern "C" void kernel_launch(void* const* d_in, const int* in_sizes, int n_in,
                              void* d_out, int out_size, void* d_ws, size_t ws_size,
                              hipStream_t stream)
{
    const void* queries = d_in[0];
    const void* Wq = d_in[1];  const void* bq = d_in[2];
    const void* Wk = d_in[3];  const void* bk = d_in[4];
    const void* Wv = d_in[5];  const void* bv = d_in[6];
    const void* Wo = d_in[7];  const void* bo = d_in[8];
    const void* ln1s = d_in[9];  const void* ln1b = d_in[10];
    const void* W1 = d_in[11]; const void* b1 = d_in[12];
    const void* W2 = d_in[13]; const void* b2 = d_in[14];
    const void* ln2s = d_in[15]; const void* ln2b = d_in[16];

    char* p = (char*)d_ws;
    int* flagp = (int*)p;             p += 256;
    ushort_t* wqkvT = (ushort_t*)p;   p += (long)CL * 3072 * 256 * 2;  // 3 MB
    ushort_t* w1T   = (ushort_t*)p;   p += (long)CL * 1024 * 256 * 2;  // 1 MB
    ushort_t* wscr  = (ushort_t*)p;   p += (long)2 * 256 * 1024 * 2;   // 1 MB
    ushort_t* xa    = (ushort_t*)p;   p += (long)NROW * CD * 2;        // 2 MB
    ushort_t* qk    = (ushort_t*)p;   p += (long)NROW * 2048 * 2;      // 16 MB
    ushort_t* vT    = (ushort_t*)p;   p += (long)16 * 256 * 1024 * 2;  // 8 MB
    ushort_t* op0   = (ushort_t*)p;   p += (long)NROW * 1024 * 2;      // 8 MB
    ushort_t* op1   = (ushort_t*)p;   p += (long)NROW * 1024 * 2;      // 8 MB
    float2*   ml    = (float2*)p;     p += (long)2 * 16 * 1024 * 8;    // 0.25 MB
    ushort_t* h     = vT;             // MLP hidden reuses vT
    float*    pgem  = (float*)qk;     // fp32 partials reuse qk (dead post-flash)

    detect_kernel<<<1, 256, 0, stream>>>((const ushort_t*)Wq, 2048, flagp);
    tconv_all<<<dim3(32, 8, 8), 256, 0, stream>>>(
        Wq, Wk, Wv, W1, wqkvT, w1T, flagp);
    in_convert<<<(NROW * CD) / 1024, 256, 0, stream>>>(queries, xa, flagp);

    for (int l = 0; l < CL; ++l) {
        // 1) merged QKV projection + Wo/W2 transpose (one dispatch)
        qkv_tconv<<<dim3(1280, 1, 1), 256, 0, stream>>>(
            xa, wqkvT + (long)l * 3072 * 256, bq, bk, bv, qk, vT,
            Wo, W2, wscr, (long)l * 1024, (long)l * 1024 * 256, flagp);
        // 2) flash attention v9 (256 blocks x 512 thr, 2 waves/SIMD)
        flash_attn<<<256, 512, 0, stream>>>(qk, vT, op0, op1, ml);
        // 3) O projection with fused partial-combine (BK=64, hoisted scales)
        mgemm64s<1><<<dim3(4, 64, 2), 256, 0, stream>>>(
            op0, op1, ml, wscr, pgem, 512, 1024, 1024);
        // 4) xa = LN(pgem0+pgem1 + bo + xa)
        ln_p<0><<<NROW, 256, 0, stream>>>(pgem, bo, (long)l * 256, xa,
                                          ln1s, ln1b, xa, (long)l * 256, flagp);
        // 5) h = relu(xa @ w1T^T + b1)  (BK=64)
        mgemm64b<1><<<dim3(16, 64, 1), 256, 0, stream>>>(
            xa, w1T + (long)l * 1024 * 256, b1, h,
            256, 256, 256, 1024, (long)l * 1024, flagp);
        // 6) MLP2 -> fp32 pgem  (BK=64)
        mgemm64s<0><<<dim3(4, 64, 2), 256, 0, stream>>>(
            h, nullptr, nullptr, wscr + 262144, pgem, 512, 1024, 1024);
        // 7) LN(pgem0+pgem1 + b2 + xa): final layer writes d_out directly
        if (l == CL - 1)
            ln_p<1><<<NROW, 256, 0, stream>>>(pgem, b2, (long)l * 256, xa,
                                              ln2s, ln2b, d_out, (long)l * 256, flagp);
        else
            ln_p<0><<<NROW, 256, 0, stream>>>(pgem, b2, (long)l * 256, xa,
                                              ln2s, ln2b, xa, (long)l * 256, flagp);
    }
}

// Round 5
// 366.199 us; speedup vs baseline: 1.0010x; 1.0010x over previous
//
#include <hip/hip_runtime.h>
#include <hip/hip_bf16.h>

#define CL 2
#define CB 4
#define CT 1024
#define CD 256
#define CH 4
#define CM 1024
#define CHD (CH * CD)      // 1024
#define NROW (CB * CT)     // 4096

typedef unsigned short ushort_t;
typedef __attribute__((ext_vector_type(8))) short short8v;   // 8 bf16 (4 VGPR)
typedef __attribute__((ext_vector_type(4))) float float4v;   // MFMA C/D frag 16x16
typedef __attribute__((ext_vector_type(16))) float float16v; // MFMA C/D frag 32x32

#define LOG2E 1.44269504088896f

__device__ __forceinline__ float bf2f(unsigned short u) {
    return __uint_as_float(((unsigned int)u) << 16);
}
__device__ __forceinline__ unsigned short f2bf(float f) {
    unsigned int x = __float_as_uint(f);
    return (unsigned short)((x + 0x7fffu + ((x >> 16) & 1u)) >> 16);
}

// ---------------------------------------------------------------------------
// Input-dtype detection (2048 elems; fp32-underlying -> ~430 anomalies, bf16 0)
// ---------------------------------------------------------------------------
__global__ __launch_bounds__(256) void detect_kernel(
    const ushort_t* __restrict__ w, int n, int* __restrict__ flag)
{
    __shared__ int red[256];
    int c = 0;
    for (int i = threadIdx.x; i < n; i += 256) {
        float v = bf2f(w[i]);
        if (!(fabsf(v) <= 1e6f)) c++;
    }
    red[threadIdx.x] = c;
    __syncthreads();
    for (int s = 128; s > 0; s >>= 1) {
        if (threadIdx.x < s) red[threadIdx.x] += red[threadIdx.x + s];
        __syncthreads();
    }
    if (threadIdx.x == 0) flag[0] = (red[0] < 8) ? 1 : 0;
}

// ---------------------------------------------------------------------------
// Prepass transpose: Wq/Wk/Wv/W1 (all [L][256][1024]) -> bf16 transposed.
// Grid (32, 8, 8): z = which*2 + l.
// ---------------------------------------------------------------------------
__global__ __launch_bounds__(256) void tconv_all(
    const void* __restrict__ Wq, const void* __restrict__ Wk,
    const void* __restrict__ Wv, const void* __restrict__ W1,
    ushort_t* __restrict__ wqkvT, ushort_t* __restrict__ w1T,
    const int* __restrict__ flagp)
{
    const int fbf = *flagp;
    const int z = blockIdx.z;
    const int which = z >> 1, l = z & 1;
    const void* in = (which == 0) ? Wq : (which == 1) ? Wk
                   : (which == 2) ? Wv : W1;
    ushort_t* out = (which < 3)
        ? wqkvT + (long)l * 3072 * 256 + (long)which * 1024 * 256
        : w1T + (long)l * 1024 * 256;
    const long zi = (long)l * 262144;

    __shared__ float tile[32][33];
    const int r0 = blockIdx.y * 32;
    const int c0 = blockIdx.x * 32;
    const int tx = threadIdx.x & 31;
    const int ty = threadIdx.x >> 5;
#pragma unroll
    for (int i = 0; i < 32; i += 8) {
        const long idx = zi + (long)(r0 + ty + i) * 1024 + c0 + tx;
        tile[ty + i][tx] = fbf ? bf2f(((const ushort_t*)in)[idx])
                               : ((const float*)in)[idx];
    }
    __syncthreads();
#pragma unroll
    for (int i = 0; i < 32; i += 8)
        out[(long)(c0 + ty + i) * 256 + r0 + tx] = f2bf(tile[tx][ty + i]);
}

// ---------------------------------------------------------------------------
// Merged QKV projection + Wo/W2 transpose (one dispatch).
// Blocks 0..767: qkv 128x128 tiles. Blocks 768..1279: tconv2.
// ---------------------------------------------------------------------------
__global__ __launch_bounds__(256) void qkv_tconv(
    const ushort_t* __restrict__ A, const ushort_t* __restrict__ B,
    const void* __restrict__ bq, const void* __restrict__ bk,
    const void* __restrict__ bv, ushort_t* __restrict__ qk,
    ushort_t* __restrict__ vT,
    const void* __restrict__ Wo, const void* __restrict__ W2,
    ushort_t* __restrict__ wscr,
    long boff, long ioff, const int* __restrict__ flagp)
{
    __shared__ __align__(16) ushort_t As[128 * 40];
    __shared__ __align__(16) ushort_t Bs[128 * 40];
    __shared__ float tile[32][33];

    const int fbf = *flagp;
    const int bx = blockIdx.x;
    const int tid = threadIdx.x;

    if (bx >= 768) {
        // ---- tconv2 part ----
        const int t = bx - 768;          // 0..511
        const int zx = t & 7;            // col-tile (256/32)
        const int zy = (t >> 3) & 31;    // row-tile (1024/32)
        const int zz = t >> 8;           // 0 = Wo, 1 = W2
        const void* in = zz ? W2 : Wo;
        ushort_t* out = wscr + (long)zz * 262144;
        const int r0 = zy * 32;
        const int c0 = zx * 32;
        const int tx = tid & 31;
        const int ty = tid >> 5;
#pragma unroll
        for (int i = 0; i < 32; i += 8) {
            const long idx = ioff + (long)(r0 + ty + i) * 256 + c0 + tx;
            tile[ty + i][tx] = fbf ? bf2f(((const ushort_t*)in)[idx])
                                   : ((const float*)in)[idx];
        }
        __syncthreads();
#pragma unroll
        for (int i = 0; i < 32; i += 8)
            out[(long)(c0 + ty + i) * 1024 + r0 + tx] = f2bf(tile[tx][ty + i]);
        return;
    }

    // ---- qkv part ----
    const int nt = bx % 24;
    const int mt = bx / 24;
    const long m0 = (long)mt * 128;
    const long n0 = (long)nt * 128;

    const int wave = tid >> 6;
    const int lane = tid & 63;
    const int quad = lane >> 4;
    const int lrow = lane & 15;
    const int wm = (wave >> 1) * 64;
    const int wn = (wave & 1) * 64;

    float4v acc[4][4];
#pragma unroll
    for (int i = 0; i < 4; ++i)
#pragma unroll
        for (int j = 0; j < 4; ++j)
            acc[i][j] = (float4v){0.f, 0.f, 0.f, 0.f};

    for (int k0 = 0; k0 < 256; k0 += 32) {
        __syncthreads();
#pragma unroll
        for (int p = 0; p < 2; ++p) {
            const int c = p * 256 + tid;
            const int row = c >> 2;
            const int kk = (c & 3) << 3;
            *reinterpret_cast<short8v*>(&As[row * 40 + kk]) =
                *reinterpret_cast<const short8v*>(&A[(m0 + row) * 256 + k0 + kk]);
            *reinterpret_cast<short8v*>(&Bs[row * 40 + kk]) =
                *reinterpret_cast<const short8v*>(&B[(n0 + row) * 256 + k0 + kk]);
        }
        __syncthreads();

        short8v af[4], bfv[4];
#pragma unroll
        for (int i = 0; i < 4; ++i) {
            af[i]  = *reinterpret_cast<const short8v*>(&As[(wm + i * 16 + lrow) * 40 + quad * 8]);
            bfv[i] = *reinterpret_cast<const short8v*>(&Bs[(wn + i * 16 + lrow) * 40 + quad * 8]);
        }
#pragma unroll
        for (int mi = 0; mi < 4; ++mi)
#pragma unroll
            for (int ni = 0; ni < 4; ++ni)
                acc[mi][ni] = __builtin_amdgcn_mfma_f32_16x16x32_bf16(
                    af[mi], bfv[ni], acc[mi][ni], 0, 0, 0);
    }

#pragma unroll
    for (int mi = 0; mi < 4; ++mi) {
#pragma unroll
        for (int ni = 0; ni < 4; ++ni) {
            const long col = n0 + wn + ni * 16 + lrow;
            const long row0 = m0 + wm + mi * 16 + quad * 4;
            const void* bp;
            long bn;
            if (col < 1024)      { bp = bq; bn = col; }
            else if (col < 2048) { bp = bk; bn = col - 1024; }
            else                 { bp = bv; bn = col - 2048; }
            const float bias = fbf ? bf2f(((const ushort_t*)bp)[boff + bn])
                                   : ((const float*)bp)[boff + bn];
            if (col < 2048) {
#pragma unroll
                for (int r = 0; r < 4; ++r)
                    qk[(row0 + r) * 2048 + col] = f2bf(acc[mi][ni][r] + bias);
            } else {
                const long d = col - 2048;
                const long addr = ((row0 >> 10) << 2) * 262144 + d * 1024 + (row0 & 1023);
                ushort4 u;
                u.x = f2bf(acc[mi][ni][0] + bias);
                u.y = f2bf(acc[mi][ni][1] + bias);
                u.z = f2bf(acc[mi][ni][2] + bias);
                u.w = f2bf(acc[mi][ni][3] + bias);
                *reinterpret_cast<ushort4*>(&vT[addr]) = u;
            }
        }
    }
}

// ---------------------------------------------------------------------------
// mgemm64s: 64x64-tile split-K GEMM -> fp32 partials. BK=64. Grid (N/64, M/64, 2).
// AMODE 1: attention-partial combine with scales HOISTED out of the k-loop.
// ---------------------------------------------------------------------------
template <int AMODE>
__global__ __launch_bounds__(256) void mgemm64s(
    const ushort_t* __restrict__ A, const ushort_t* __restrict__ Ap1,
    const float2* __restrict__ ml, const ushort_t* __restrict__ B,
    float* __restrict__ P, int K2, int lda, int ldb)
{
    const int z = blockIdx.z;
    const long m0 = (long)blockIdx.y * 64;
    const long n0 = (long)blockIdx.x * 64;
    const int k_beg = z * K2;

    __shared__ __align__(16) ushort_t As[64 * 72];
    __shared__ __align__(16) ushort_t Bs[64 * 72];

    const int tid = threadIdx.x;
    const int wave = tid >> 6;
    const int lane = tid & 63;
    const int quad = lane >> 4;
    const int lrow = lane & 15;
    const int wm = (wave >> 1) * 32;
    const int wn = (wave & 1) * 32;

    const int ar = tid >> 2;          // 0..63
    const int ak = (tid & 3) << 3;    // 0,8,16,24

    float s0h[2] = {0.f, 0.f}, s1h[2] = {0.f, 0.f};
    if constexpr (AMODE == 1) {
        const long m = m0 + ar;
        const int bhbase = ((int)(m >> 10) << 2);
        const int trow = (int)(m & 1023);
        const int h0 = k_beg >> 8;
#pragma unroll
        for (int i = 0; i < 2; ++i) {
            const int bh = bhbase + h0 + i;
            const float2 v0 = ml[bh * 1024 + trow];
            const float2 v1 = ml[(16 + bh) * 1024 + trow];
            const float mm = fmaxf(v0.x, v1.x);
            const float a0 = exp2f(v0.x - mm);
            const float a1 = exp2f(v1.x - mm);
            const float inv = 1.0f / (v0.y * a0 + v1.y * a1);
            s0h[i] = a0 * inv;
            s1h[i] = a1 * inv;
        }
    }

    float4v acc[2][2];
#pragma unroll
    for (int i = 0; i < 2; ++i)
#pragma unroll
        for (int j = 0; j < 2; ++j)
            acc[i][j] = (float4v){0.f, 0.f, 0.f, 0.f};

    for (int k0 = k_beg; k0 < k_beg + K2; k0 += 64) {
        __syncthreads();
#pragma unroll
        for (int p = 0; p < 2; ++p) {
            const int kc = p * 32 + ak;
            if constexpr (AMODE == 0) {
                *reinterpret_cast<short8v*>(&As[ar * 72 + kc]) =
                    *reinterpret_cast<const short8v*>(&A[(m0 + ar) * (long)lda + k0 + kc]);
            } else {
                const long m = m0 + ar;
                const int hi = ((k0 + kc) >> 8) - (k_beg >> 8);   // 0 or 1
                const float s0 = s0h[hi], s1 = s1h[hi];
                const ushort4 u0a = *reinterpret_cast<const ushort4*>(&A[m * 1024 + k0 + kc]);
                const ushort4 u0b = *reinterpret_cast<const ushort4*>(&A[m * 1024 + k0 + kc + 4]);
                const ushort4 u1a = *reinterpret_cast<const ushort4*>(&Ap1[m * 1024 + k0 + kc]);
                const ushort4 u1b = *reinterpret_cast<const ushort4*>(&Ap1[m * 1024 + k0 + kc + 4]);
                short8v t8;
                t8[0] = (short)f2bf(bf2f(u0a.x) * s0 + bf2f(u1a.x) * s1);
                t8[1] = (short)f2bf(bf2f(u0a.y) * s0 + bf2f(u1a.y) * s1);
                t8[2] = (short)f2bf(bf2f(u0a.z) * s0 + bf2f(u1a.z) * s1);
                t8[3] = (short)f2bf(bf2f(u0a.w) * s0 + bf2f(u1a.w) * s1);
                t8[4] = (short)f2bf(bf2f(u0b.x) * s0 + bf2f(u1b.x) * s1);
                t8[5] = (short)f2bf(bf2f(u0b.y) * s0 + bf2f(u1b.y) * s1);
                t8[6] = (short)f2bf(bf2f(u0b.z) * s0 + bf2f(u1b.z) * s1);
                t8[7] = (short)f2bf(bf2f(u0b.w) * s0 + bf2f(u1b.w) * s1);
                *reinterpret_cast<short8v*>(&As[ar * 72 + kc]) = t8;
            }
            *reinterpret_cast<short8v*>(&Bs[ar * 72 + kc]) =
                *reinterpret_cast<const short8v*>(&B[(n0 + ar) * (long)ldb + k0 + kc]);
        }
        __syncthreads();

#pragma unroll
        for (int kk = 0; kk < 2; ++kk) {
            short8v af[2], bfv[2];
#pragma unroll
            for (int i = 0; i < 2; ++i) {
                af[i]  = *reinterpret_cast<const short8v*>(
                    &As[(wm + i * 16 + lrow) * 72 + kk * 32 + quad * 8]);
                bfv[i] = *reinterpret_cast<const short8v*>(
                    &Bs[(wn + i * 16 + lrow) * 72 + kk * 32 + quad * 8]);
            }
#pragma unroll
            for (int mi = 0; mi < 2; ++mi)
#pragma unroll
                for (int ni = 0; ni < 2; ++ni)
                    acc[mi][ni] = __builtin_amdgcn_mfma_f32_16x16x32_bf16(
                        af[mi], bfv[ni], acc[mi][ni], 0, 0, 0);
        }
    }

    float* Pz = P + (long)z * NROW * CD;
#pragma unroll
    for (int mi = 0; mi < 2; ++mi)
#pragma unroll
        for (int ni = 0; ni < 2; ++ni) {
            const long col = n0 + wn + ni * 16 + lrow;
            const long row0 = m0 + wm + mi * 16 + quad * 4;
#pragma unroll
            for (int r = 0; r < 4; ++r)
                Pz[(row0 + r) * CD + col] = acc[mi][ni][r];
        }
}

// ---------------------------------------------------------------------------
// mgemm64b: 64x64-tile full-K GEMM (MLP1), BK=64, bias+relu, bf16 out.
// ---------------------------------------------------------------------------
template <int RELU>
__global__ __launch_bounds__(256) void mgemm64b(
    const ushort_t* __restrict__ A, const ushort_t* __restrict__ B,
    const void* __restrict__ bias, ushort_t* __restrict__ C,
    int K, int lda, int ldb, int ldc, long boff,
    const int* __restrict__ flagp)
{
    const long m0 = (long)blockIdx.y * 64;
    const long n0 = (long)blockIdx.x * 64;

    __shared__ __align__(16) ushort_t As[64 * 72];
    __shared__ __align__(16) ushort_t Bs[64 * 72];

    const int tid = threadIdx.x;
    const int wave = tid >> 6;
    const int lane = tid & 63;
    const int quad = lane >> 4;
    const int lrow = lane & 15;
    const int wm = (wave >> 1) * 32;
    const int wn = (wave & 1) * 32;

    const int ar = tid >> 2;
    const int ak = (tid & 3) << 3;

    float4v acc[2][2];
#pragma unroll
    for (int i = 0; i < 2; ++i)
#pragma unroll
        for (int j = 0; j < 2; ++j)
            acc[i][j] = (float4v){0.f, 0.f, 0.f, 0.f};

    for (int k0 = 0; k0 < K; k0 += 64) {
        __syncthreads();
#pragma unroll
        for (int p = 0; p < 2; ++p) {
            const int kc = p * 32 + ak;
            *reinterpret_cast<short8v*>(&As[ar * 72 + kc]) =
                *reinterpret_cast<const short8v*>(&A[(m0 + ar) * (long)lda + k0 + kc]);
            *reinterpret_cast<short8v*>(&Bs[ar * 72 + kc]) =
                *reinterpret_cast<const short8v*>(&B[(n0 + ar) * (long)ldb + k0 + kc]);
        }
        __syncthreads();

#pragma unroll
        for (int kk = 0; kk < 2; ++kk) {
            short8v af[2], bfv[2];
#pragma unroll
            for (int i = 0; i < 2; ++i) {
                af[i]  = *reinterpret_cast<const short8v*>(
                    &As[(wm + i * 16 + lrow) * 72 + kk * 32 + quad * 8]);
                bfv[i] = *reinterpret_cast<const short8v*>(
                    &Bs[(wn + i * 16 + lrow) * 72 + kk * 32 + quad * 8]);
            }
#pragma unroll
            for (int mi = 0; mi < 2; ++mi)
#pragma unroll
                for (int ni = 0; ni < 2; ++ni)
                    acc[mi][ni] = __builtin_amdgcn_mfma_f32_16x16x32_bf16(
                        af[mi], bfv[ni], acc[mi][ni], 0, 0, 0);
        }
    }

    const int fbf = *flagp;
#pragma unroll
    for (int mi = 0; mi < 2; ++mi)
#pragma unroll
        for (int ni = 0; ni < 2; ++ni) {
            const long col = n0 + wn + ni * 16 + lrow;
            const long row0 = m0 + wm + mi * 16 + quad * 4;
            const float bv = fbf ? bf2f(((const ushort_t*)bias)[boff + col])
                                 : ((const float*)bias)[boff + col];
#pragma unroll
            for (int r = 0; r < 4; ++r) {
                float v = acc[mi][ni][r] + bv;
                if (RELU) v = fmaxf(v, 0.f);
                C[(row0 + r) * (long)ldc + col] = f2bf(v);
            }
        }
}

// ---------------------------------------------------------------------------
// Flash attention v10: v9 with the launch-bounds spill bug fixed.
//  v9 POST-MORTEM: __launch_bounds__(512,2) was applied by hipcc with
//  min-BLOCKS semantics -> 16 waves/CU -> 128-VGPR cap -> ~110 VGPR of live
//  state spilled to scratch (FETCH 12.4->90 MB, WRITE 16.6->59.6 MB, 75 us).
//  Fix: __launch_bounds__(512, 1). A 512-thread block forces 8 waves on
//  4 SIMDs = 2 waves/SIMD, so the implied VGPR cap is 256 >= the ~240 this
//  kernel needs (v8 compiled to 240). Everything else identical to v9:
//  - 256 blocks x 512 thr; waves 0..3 = q-subtiles on kv-half A, 4..7 on B.
//  - ping-pong x 2 halves K/V LDS (144 KB), reg-staged prefetch, 1 barrier/tile.
//  - K XOR-swizzle (conflicts 5.6M->0.5M, proven v8), defer-max THR=8 (T13).
//  - End-of-block pair-combine via LDS -> op/ml identical to v8 semantics.
// ---------------------------------------------------------------------------
__global__ __launch_bounds__(512, 1) void flash_attn(
    const ushort_t* __restrict__ qk, const ushort_t* __restrict__ vT,
    ushort_t* __restrict__ op0, ushort_t* __restrict__ op1,
    float2* __restrict__ ml)
{
    const int bx = blockIdx.x;
    const int bh = bx & 15;           // b*4 + h
    const int qg = (bx >> 4) & 7;     // 128-row q-group
    const int ck = bx >> 7;           // key-chunk 0/1
    const int bb = bh >> 2, h = bh & 3;

    // [buf][half] K: 32x256 swizzled at  (buf*2+half)*8192
    // [buf][half] V: 256x40 padded at 32768 + (buf*2+half)*10240
    // epilogue reuse: xO = 4 x 8192 floats (128 KB), xml at byte 131072.
    __shared__ __align__(16) ushort_t smem[73728];   // 144 KB

    const int tid = threadIdx.x;      // 0..511
    const int wave = tid >> 6;        // 0..7
    const int lane = tid & 63;
    const int col = lane & 31;
    const int hi = lane >> 5;
    const int hi8 = hi << 3;

    const int qsub = wave & 3;        // q-subtile within the 128-row group
    const int hf = wave >> 2;         // kv-half this wave consumes

    const long qrow0w = (long)bb * CT + qg * 128 + qsub * 32;
    const int qcol = h * 256;
    const int kcol = 1024 + h * 256;
    const long vbase = (long)bh * 256 * 1024;
    const float SC = 0.0625f * LOG2E;

    // staging: threads 0-255 stage half 0, threads 256-511 stage half 1
    const int sh = tid >> 8;
    const int st = tid & 255;
    const int kr_ = st >> 5;           // 0..7
    const int kc_ = (st & 31) << 3;    // 0..248
    const int vr_ = st >> 2;           // 0..63
    const int vc_ = (st & 3) << 3;     // 0..24
    const int t0s = ck * 512 + sh * 256;   // staging key base (this thread)
    ushort_t* KsS = smem + sh * 8192;              // + buf*16384
    ushort_t* VsS = smem + 32768 + sh * 10240;     // + buf*20480

    short8v kreg[4], vreg[4];
#pragma unroll
    for (int i = 0; i < 4; ++i) {
        kreg[i] = *reinterpret_cast<const short8v*>(
            &qk[((long)bb * CT + t0s + i * 8 + kr_) * 2048 + kcol + kc_]);
        vreg[i] = *reinterpret_cast<const short8v*>(
            &vT[vbase + (long)(i * 64 + vr_) * 1024 + t0s + vc_]);
    }

    // Q B-frags: lane holds Q[qrow0w + col][s*16 + hi*8 .. +7]
    short8v qf[16];
#pragma unroll
    for (int s = 0; s < 16; ++s)
        qf[s] = *reinterpret_cast<const short8v*>(
            &qk[(qrow0w + col) * 2048 + qcol + s * 16 + hi8]);

    float mrun = -1e30f, lrun = 0.f;
    float16v oacc[8];
#pragma unroll
    for (int i = 0; i < 8; ++i)
#pragma unroll
        for (int j = 0; j < 16; ++j) oacc[i][j] = 0.f;

    // stage tile 0 into buf 0 (K swizzled: phys 16B-chunk = logical ^ row)
#pragma unroll
    for (int i = 0; i < 4; ++i) {
        const int kr = i * 8 + kr_;
        *reinterpret_cast<short8v*>(&KsS[kr * 256 + (((st & 31) ^ kr) << 3)]) = kreg[i];
        *reinterpret_cast<short8v*>(&VsS[(i * 64 + vr_) * 40 + vc_]) = vreg[i];
    }
    __syncthreads();

    // compute-side bases for this wave's half
    ushort_t* KsW = smem + hf * 8192;              // + cur*16384
    ushort_t* VsW = smem + 32768 + hf * 10240;     // + cur*20480
    const int krowbase = col * 256;
    const int kxor = col << 4;

    for (int it = 0; it < 8; ++it) {
        const int cur = it & 1;

        // prefetch tile it+1 into registers (consumed after compute)
        if (it < 7) {
            const int tn = t0s + (it + 1) * 32;
#pragma unroll
            for (int i = 0; i < 4; ++i) {
                kreg[i] = *reinterpret_cast<const short8v*>(
                    &qk[((long)bb * CT + tn + i * 8 + kr_) * 2048 + kcol + kc_]);
                vreg[i] = *reinterpret_cast<const short8v*>(
                    &vT[vbase + (long)(i * 64 + vr_) * 1024 + tn + vc_]);
            }
        }

        // ---- QK^T -> S^T[t][q]  (2-way split acc)
        const ushort_t* Kc = KsW + cur * 16384;
        float16v sa, sb;
#pragma unroll
        for (int j = 0; j < 16; ++j) { sa[j] = 0.f; sb[j] = 0.f; }
        __builtin_amdgcn_s_setprio(1);
#pragma unroll
        for (int s = 0; s < 16; s += 2) {
            const int o0 = ((s * 32 + hi * 16) ^ kxor) >> 1;
            const int o1 = (((s + 1) * 32 + hi * 16) ^ kxor) >> 1;
            const short8v k0 = *reinterpret_cast<const short8v*>(&Kc[krowbase + o0]);
            const short8v k1 = *reinterpret_cast<const short8v*>(&Kc[krowbase + o1]);
            sa = __builtin_amdgcn_mfma_f32_32x32x16_bf16(k0, qf[s], sa, 0, 0, 0);
            sb = __builtin_amdgcn_mfma_f32_32x32x16_bf16(k1, qf[s + 1], sb, 0, 0, 0);
        }
        __builtin_amdgcn_s_setprio(0);

        float sv[16];
#pragma unroll
        for (int j = 0; j < 16; ++j) sv[j] = (sa[j] + sb[j]) * SC;

        // ---- row max (q = lane&31; lane l^32 holds the other 16 k's)
        float mx = sv[0];
#pragma unroll
        for (int j = 1; j < 16; ++j) mx = fmaxf(mx, sv[j]);
        mx = fmaxf(mx, __shfl_xor(mx, 32));

        if (__ballot(mx > mrun + 8.0f) != 0ull) {   // T13 defer-max THR=8
            const float mnew = fmaxf(mrun, mx);
            const float alpha = exp2f(mrun - mnew);
            mrun = mnew;
            lrun *= alpha;
            float ar[16];
#pragma unroll
            for (int r = 0; r < 16; ++r)
                ar[r] = __shfl(alpha, (r & 3) + 8 * (r >> 2) + (hi << 2));
#pragma unroll
            for (int dt = 0; dt < 8; ++dt)
#pragma unroll
                for (int r = 0; r < 16; ++r)
                    oacc[dt][r] *= ar[r];
        }

        // ---- P = exp2(S - m), l-sum
        float p[16];
        float s = 0.f;
#pragma unroll
        for (int j = 0; j < 16; ++j) { p[j] = exp2f(sv[j] - mrun); s += p[j]; }
        s += __shfl_xor(s, 32);
        lrun += s;

        // ---- pack P to bf16 PV A-frags (half-exchange via shfl_xor 32)
        const unsigned c01 = (unsigned)f2bf(p[0])  | ((unsigned)f2bf(p[1])  << 16);
        const unsigned c23 = (unsigned)f2bf(p[2])  | ((unsigned)f2bf(p[3])  << 16);
        const unsigned c45 = (unsigned)f2bf(p[4])  | ((unsigned)f2bf(p[5])  << 16);
        const unsigned c67 = (unsigned)f2bf(p[6])  | ((unsigned)f2bf(p[7])  << 16);
        const unsigned d01 = (unsigned)f2bf(p[8])  | ((unsigned)f2bf(p[9])  << 16);
        const unsigned d23 = (unsigned)f2bf(p[10]) | ((unsigned)f2bf(p[11]) << 16);
        const unsigned d45 = (unsigned)f2bf(p[12]) | ((unsigned)f2bf(p[13]) << 16);
        const unsigned d67 = (unsigned)f2bf(p[14]) | ((unsigned)f2bf(p[15]) << 16);
        const unsigned x01 = __shfl_xor(c01, 32);
        const unsigned x23 = __shfl_xor(c23, 32);
        const unsigned x45 = __shfl_xor(c45, 32);
        const unsigned x67 = __shfl_xor(c67, 32);
        const unsigned y01 = __shfl_xor(d01, 32);
        const unsigned y23 = __shfl_xor(d23, 32);
        const unsigned y45 = __shfl_xor(d45, 32);
        const unsigned y67 = __shfl_xor(d67, 32);
        union { unsigned u[4]; short8v v; } pf0, pf1;
        pf0.u[0] = hi ? x45 : c01;
        pf0.u[1] = hi ? x67 : c23;
        pf0.u[2] = hi ? c45 : x01;
        pf0.u[3] = hi ? c67 : x23;
        pf1.u[0] = hi ? y45 : d01;
        pf1.u[1] = hi ? y67 : d23;
        pf1.u[2] = hi ? d45 : y01;
        pf1.u[3] = hi ? d67 : y23;

        // ---- PV: O[q][d] += P * V   (8 independent d-tiles)
        const ushort_t* Vc = VsW + cur * 20480;
        __builtin_amdgcn_s_setprio(1);
#pragma unroll
        for (int dt = 0; dt < 8; ++dt) {
            const int vb = (dt * 32 + col) * 40 + hi8;
            const short8v v0 = *reinterpret_cast<const short8v*>(&Vc[vb]);
            const short8v v1 = *reinterpret_cast<const short8v*>(&Vc[vb + 16]);
            oacc[dt] = __builtin_amdgcn_mfma_f32_32x32x16_bf16(pf0.v, v0, oacc[dt], 0, 0, 0);
            oacc[dt] = __builtin_amdgcn_mfma_f32_32x32x16_bf16(pf1.v, v1, oacc[dt], 0, 0, 0);
        }
        __builtin_amdgcn_s_setprio(0);

        // ---- write prefetched tile into the other buffer; one barrier/tile
        if (it < 7) {
            const int nb = cur ^ 1;
#pragma unroll
            for (int i = 0; i < 4; ++i) {
                const int kr = i * 8 + kr_;
                *reinterpret_cast<short8v*>(
                    &KsS[nb * 16384 + kr * 256 + (((st & 31) ^ kr) << 3)]) = kreg[i];
                *reinterpret_cast<short8v*>(
                    &VsS[nb * 20480 + (i * 64 + vr_) * 40 + vc_]) = vreg[i];
            }
            __syncthreads();
        }
    }

    // ---- in-block combine of the two kv-halves (pairs w <-> w+4) ----
    __syncthreads();                               // K/V LDS now dead
    float* xO = (float*)smem;                      // [qsub][dt*16+r][hi*32+col]
    float2* xml = (float2*)((char*)smem + 131072); // [qsub*32 + q]

    if (hf == 1) {
#pragma unroll
        for (int dt = 0; dt < 8; ++dt)
#pragma unroll
            for (int r = 0; r < 16; ++r)
                xO[qsub * 8192 + (dt * 16 + r) * 64 + (hi << 5) + col] = oacc[dt][r];
        if (hi == 0)
            xml[qsub * 32 + col] = make_float2(mrun, lrun);
    }
    __syncthreads();

    if (hf == 0) {
        const float2 o2 = xml[qsub * 32 + col];
        const float mstar = fmaxf(mrun, o2.x);
        const float a0 = exp2f(mrun - mstar);
        const float a2 = exp2f(o2.x - mstar);
        const float lnew = lrun * a0 + o2.y * a2;
        float ar0[16], ar2[16];
#pragma unroll
        for (int r = 0; r < 16; ++r) {
            const int li = (r & 3) + 8 * (r >> 2) + (hi << 2);
            ar0[r] = __shfl(a0, li);
            ar2[r] = __shfl(a2, li);
        }
        if (lane < 32) {
            const int trow = (int)((qrow0w + lane) & 1023);
            ml[((ck << 4) + bh) * 1024 + trow] = make_float2(mstar, lnew);
        }
        ushort_t* op = ck ? op1 : op0;
#pragma unroll
        for (int dt = 0; dt < 8; ++dt)
#pragma unroll
            for (int r = 0; r < 16; ++r) {
                const int row = (r & 3) + 8 * (r >> 2) + (hi << 2);
                const float of = oacc[dt][r] * ar0[r]
                    + xO[qsub * 8192 + (dt * 16 + r) * 64 + (hi << 5) + col] * ar2[r];
                op[(qrow0w + row) * 1024 + (h << 8) + dt * 32 + col] = f2bf(of);
            }
    }
}

// ---------------------------------------------------------------------------
// ln_p: x = P0[row]+P1[row] + gbias + res; y = LN(x)*s + b.
// FINAL=1 writes d_out in flag dtype.
// ---------------------------------------------------------------------------
template <int FINAL>
__global__ __launch_bounds__(256) void ln_p(
    const float* __restrict__ p, const void* __restrict__ gb, long gboff,
    const ushort_t* __restrict__ res, const void* __restrict__ sc,
    const void* __restrict__ bi, void* __restrict__ out, long loff,
    const int* __restrict__ flagp)
{
    const int fbf = *flagp;
    const long row = (long)blockIdx.x * CD;
    const int t = threadIdx.x;
    const float gbv = fbf ? bf2f(((const ushort_t*)gb)[gboff + t])
                          : ((const float*)gb)[gboff + t];
    const float x = p[row + t] + p[(long)NROW * CD + row + t] + gbv + bf2f(res[row + t]);

    __shared__ float r1[256];
    __shared__ float r2[256];
    r1[t] = x;
    r2[t] = x * x;
    __syncthreads();
    for (int s = 128; s > 0; s >>= 1) {
        if (t < s) { r1[t] += r1[t + s]; r2[t] += r2[t + s]; }
        __syncthreads();
    }
    const float mean = r1[0] * (1.0f / CD);
    const float var = r2[0] * (1.0f / CD) - mean * mean;
    const float rstd = rsqrtf(var + 1e-5f);
    const float s_v = fbf ? bf2f(((const ushort_t*)sc)[loff + t]) : ((const float*)sc)[loff + t];
    const float b_v = fbf ? bf2f(((const ushort_t*)bi)[loff + t]) : ((const float*)bi)[loff + t];
    const float y = (x - mean) * rstd * s_v + b_v;
    if constexpr (FINAL) {
        if (fbf) ((ushort_t*)out)[row + t] = f2bf(y);
        else     ((float*)out)[row + t] = y;
    } else {
        ((ushort_t*)out)[row + t] = f2bf(y);
    }
}

__global__ __launch_bounds__(256) void in_convert(
    const void* __restrict__ in, ushort_t* __restrict__ x,
    const int* __restrict__ flagp)
{
    const int fbf = *flagp;
    const long i = ((long)blockIdx.x * 256 + threadIdx.x) << 2;
    if (fbf) {
        *reinterpret_cast<ushort4*>(x + i) =
            *reinterpret_cast<const ushort4*>((const ushort_t*)in + i);
    } else {
        float4 f = *reinterpret_cast<const float4*>((const float*)in + i);
        ushort4 u;
        u.x = f2bf(f.x); u.y = f2bf(f.y); u.z = f2bf(f.z); u.w = f2bf(f.w);
        *reinterpret_cast<ushort4*>(x + i) = u;
    }
}

// ---------------------------------------------------------------------------
// Orchestration. ws = 47.25 MB + 256 B. Dispatches: 3 + 7/layer x 2 = 17.
// ---------------------------------------------------------------------------
extern "C" void kernel_launch(void* const* d_in, const int* in_sizes, int n_in,
                              void* d_out, int out_size, void* d_ws, size_t ws_size,
                              hipStream_t stream)
{
    const void* queries = d_in[0];
    const void* Wq = d_in[1];  const void* bq = d_in[2];
    const void* Wk = d_in[3];  const void* bk = d_in[4];
    const void* Wv = d_in[5];  const void* bv = d_in[6];
    const void* Wo = d_in[7];  const void* bo = d_in[8];
    const void* ln1s = d_in[9];  const void* ln1b = d_in[10];
    const void* W1 = d_in[11]; const void* b1 = d_in[12];
    const void* W2 = d_in[13]; const void* b2 = d_in[14];
    const void* ln2s = d_in[15]; const void* ln2b = d_in[16];

    char* p = (char*)d_ws;
    int* flagp = (int*)p;             p += 256;
    ushort_t* wqkvT = (ushort_t*)p;   p += (long)CL * 3072 * 256 * 2;  // 3 MB
    ushort_t* w1T   = (ushort_t*)p;   p += (long)CL * 1024 * 256 * 2;  // 1 MB
    ushort_t* wscr  = (ushort_t*)p;   p += (long)2 * 256 * 1024 * 2;   // 1 MB
    ushort_t* xa    = (ushort_t*)p;   p += (long)NROW * CD * 2;        // 2 MB
    ushort_t* qk    = (ushort_t*)p;   p += (long)NROW * 2048 * 2;      // 16 MB
    ushort_t* vT    = (ushort_t*)p;   p += (long)16 * 256 * 1024 * 2;  // 8 MB
    ushort_t* op0   = (ushort_t*)p;   p += (long)NROW * 1024 * 2;      // 8 MB
    ushort_t* op1   = (ushort_t*)p;   p += (long)NROW * 1024 * 2;      // 8 MB
    float2*   ml    = (float2*)p;     p += (long)2 * 16 * 1024 * 8;    // 0.25 MB
    ushort_t* h     = vT;             // MLP hidden reuses vT
    float*    pgem  = (float*)qk;     // fp32 partials reuse qk (dead post-flash)

    detect_kernel<<<1, 256, 0, stream>>>((const ushort_t*)Wq, 2048, flagp);
    tconv_all<<<dim3(32, 8, 8), 256, 0, stream>>>(
        Wq, Wk, Wv, W1, wqkvT, w1T, flagp);
    in_convert<<<(NROW * CD) / 1024, 256, 0, stream>>>(queries, xa, flagp);

    for (int l = 0; l < CL; ++l) {
        // 1) merged QKV projection + Wo/W2 transpose (one dispatch)
        qkv_tconv<<<dim3(1280, 1, 1), 256, 0, stream>>>(
            xa, wqkvT + (long)l * 3072 * 256, bq, bk, bv, qk, vT,
            Wo, W2, wscr, (long)l * 1024, (long)l * 1024 * 256, flagp);
        // 2) flash attention v10 (256 blocks x 512 thr, 2 waves/SIMD, no spill)
        flash_attn<<<256, 512, 0, stream>>>(qk, vT, op0, op1, ml);
        // 3) O projection with fused partial-combine (BK=64, hoisted scales)
        mgemm64s<1><<<dim3(4, 64, 2), 256, 0, stream>>>(
            op0, op1, ml, wscr, pgem, 512, 1024, 1024);
        // 4) xa = LN(pgem0+pgem1 + bo + xa)
        ln_p<0><<<NROW, 256, 0, stream>>>(pgem, bo, (long)l * 256, xa,
                                          ln1s, ln1b, xa, (long)l * 256, flagp);
        // 5) h = relu(xa @ w1T^T + b1)  (BK=64)
        mgemm64b<1><<<dim3(16, 64, 1), 256, 0, stream>>>(
            xa, w1T + (long)l * 1024 * 256, b1, h,
            256, 256, 256, 1024, (long)l * 1024, flagp);
        // 6) MLP2 -> fp32 pgem  (BK=64)
        mgemm64s<0><<<dim3(4, 64, 2), 256, 0, stream>>>(
            h, nullptr, nullptr, wscr + 262144, pgem, 512, 1024, 1024);
        // 7) LN(pgem0+pgem1 + b2 + xa): final layer writes d_out directly
        if (l == CL - 1)
            ln_p<1><<<NROW, 256, 0, stream>>>(pgem, b2, (long)l * 256, xa,
                                              ln2s, ln2b, d_out, (long)l * 256, flagp);
        else
            ln_p<0><<<NROW, 256, 0, stream>>>(pgem, b2, (long)l * 256, xa,
                                              ln2s, ln2b, xa, (long)l * 256, flagp);
    }
}

// Round 6
// 344.816 us; speedup vs baseline: 1.0631x; 1.0620x over previous
//
#include <hip/hip_runtime.h>
#include <hip/hip_bf16.h>

#define CL 2
#define CB 4
#define CT 1024
#define CD 256
#define CH 4
#define CM 1024
#define CHD (CH * CD)      // 1024
#define NROW (CB * CT)     // 4096

typedef unsigned short ushort_t;
typedef __attribute__((ext_vector_type(8))) short short8v;   // 8 bf16 (4 VGPR)
typedef __attribute__((ext_vector_type(4))) float float4v;   // MFMA C/D frag 16x16
typedef __attribute__((ext_vector_type(16))) float float16v; // MFMA C/D frag 32x32

#define LOG2E 1.44269504088896f

__device__ __forceinline__ float bf2f(unsigned short u) {
    return __uint_as_float(((unsigned int)u) << 16);
}
__device__ __forceinline__ unsigned short f2bf(float f) {
    unsigned int x = __float_as_uint(f);
    return (unsigned short)((x + 0x7fffu + ((x >> 16) & 1u)) >> 16);
}

// ---------------------------------------------------------------------------
// Input-dtype detection (2048 elems; fp32-underlying -> ~430 anomalies, bf16 0)
// ---------------------------------------------------------------------------
__global__ __launch_bounds__(256) void detect_kernel(
    const ushort_t* __restrict__ w, int n, int* __restrict__ flag)
{
    __shared__ int red[256];
    int c = 0;
    for (int i = threadIdx.x; i < n; i += 256) {
        float v = bf2f(w[i]);
        if (!(fabsf(v) <= 1e6f)) c++;
    }
    red[threadIdx.x] = c;
    __syncthreads();
    for (int s = 128; s > 0; s >>= 1) {
        if (threadIdx.x < s) red[threadIdx.x] += red[threadIdx.x + s];
        __syncthreads();
    }
    if (threadIdx.x == 0) flag[0] = (red[0] < 8) ? 1 : 0;
}

// ---------------------------------------------------------------------------
// Prepass transpose: Wq/Wk/Wv/W1 (all [L][256][1024]) -> bf16 transposed.
// Grid (32, 8, 8): z = which*2 + l.
// ---------------------------------------------------------------------------
__global__ __launch_bounds__(256) void tconv_all(
    const void* __restrict__ Wq, const void* __restrict__ Wk,
    const void* __restrict__ Wv, const void* __restrict__ W1,
    ushort_t* __restrict__ wqkvT, ushort_t* __restrict__ w1T,
    const int* __restrict__ flagp)
{
    const int fbf = *flagp;
    const int z = blockIdx.z;
    const int which = z >> 1, l = z & 1;
    const void* in = (which == 0) ? Wq : (which == 1) ? Wk
                   : (which == 2) ? Wv : W1;
    ushort_t* out = (which < 3)
        ? wqkvT + (long)l * 3072 * 256 + (long)which * 1024 * 256
        : w1T + (long)l * 1024 * 256;
    const long zi = (long)l * 262144;

    __shared__ float tile[32][33];
    const int r0 = blockIdx.y * 32;
    const int c0 = blockIdx.x * 32;
    const int tx = threadIdx.x & 31;
    const int ty = threadIdx.x >> 5;
#pragma unroll
    for (int i = 0; i < 32; i += 8) {
        const long idx = zi + (long)(r0 + ty + i) * 1024 + c0 + tx;
        tile[ty + i][tx] = fbf ? bf2f(((const ushort_t*)in)[idx])
                               : ((const float*)in)[idx];
    }
    __syncthreads();
#pragma unroll
    for (int i = 0; i < 32; i += 8)
        out[(long)(c0 + ty + i) * 256 + r0 + tx] = f2bf(tile[tx][ty + i]);
}

// ---------------------------------------------------------------------------
// Merged QKV projection + Wo/W2 transpose (one dispatch).
// Blocks 0..767: qkv 128x128 tiles. Blocks 768..1279: tconv2.
// ---------------------------------------------------------------------------
__global__ __launch_bounds__(256) void qkv_tconv(
    const ushort_t* __restrict__ A, const ushort_t* __restrict__ B,
    const void* __restrict__ bq, const void* __restrict__ bk,
    const void* __restrict__ bv, ushort_t* __restrict__ qk,
    ushort_t* __restrict__ vT,
    const void* __restrict__ Wo, const void* __restrict__ W2,
    ushort_t* __restrict__ wscr,
    long boff, long ioff, const int* __restrict__ flagp)
{
    __shared__ __align__(16) ushort_t As[128 * 40];
    __shared__ __align__(16) ushort_t Bs[128 * 40];
    __shared__ float tile[32][33];

    const int fbf = *flagp;
    const int bx = blockIdx.x;
    const int tid = threadIdx.x;

    if (bx >= 768) {
        // ---- tconv2 part ----
        const int t = bx - 768;          // 0..511
        const int zx = t & 7;            // col-tile (256/32)
        const int zy = (t >> 3) & 31;    // row-tile (1024/32)
        const int zz = t >> 8;           // 0 = Wo, 1 = W2
        const void* in = zz ? W2 : Wo;
        ushort_t* out = wscr + (long)zz * 262144;
        const int r0 = zy * 32;
        const int c0 = zx * 32;
        const int tx = tid & 31;
        const int ty = tid >> 5;
#pragma unroll
        for (int i = 0; i < 32; i += 8) {
            const long idx = ioff + (long)(r0 + ty + i) * 256 + c0 + tx;
            tile[ty + i][tx] = fbf ? bf2f(((const ushort_t*)in)[idx])
                                   : ((const float*)in)[idx];
        }
        __syncthreads();
#pragma unroll
        for (int i = 0; i < 32; i += 8)
            out[(long)(c0 + ty + i) * 1024 + r0 + tx] = f2bf(tile[tx][ty + i]);
        return;
    }

    // ---- qkv part ----
    const int nt = bx % 24;
    const int mt = bx / 24;
    const long m0 = (long)mt * 128;
    const long n0 = (long)nt * 128;

    const int wave = tid >> 6;
    const int lane = tid & 63;
    const int quad = lane >> 4;
    const int lrow = lane & 15;
    const int wm = (wave >> 1) * 64;
    const int wn = (wave & 1) * 64;

    float4v acc[4][4];
#pragma unroll
    for (int i = 0; i < 4; ++i)
#pragma unroll
        for (int j = 0; j < 4; ++j)
            acc[i][j] = (float4v){0.f, 0.f, 0.f, 0.f};

    for (int k0 = 0; k0 < 256; k0 += 32) {
        __syncthreads();
#pragma unroll
        for (int p = 0; p < 2; ++p) {
            const int c = p * 256 + tid;
            const int row = c >> 2;
            const int kk = (c & 3) << 3;
            *reinterpret_cast<short8v*>(&As[row * 40 + kk]) =
                *reinterpret_cast<const short8v*>(&A[(m0 + row) * 256 + k0 + kk]);
            *reinterpret_cast<short8v*>(&Bs[row * 40 + kk]) =
                *reinterpret_cast<const short8v*>(&B[(n0 + row) * 256 + k0 + kk]);
        }
        __syncthreads();

        short8v af[4], bfv[4];
#pragma unroll
        for (int i = 0; i < 4; ++i) {
            af[i]  = *reinterpret_cast<const short8v*>(&As[(wm + i * 16 + lrow) * 40 + quad * 8]);
            bfv[i] = *reinterpret_cast<const short8v*>(&Bs[(wn + i * 16 + lrow) * 40 + quad * 8]);
        }
#pragma unroll
        for (int mi = 0; mi < 4; ++mi)
#pragma unroll
            for (int ni = 0; ni < 4; ++ni)
                acc[mi][ni] = __builtin_amdgcn_mfma_f32_16x16x32_bf16(
                    af[mi], bfv[ni], acc[mi][ni], 0, 0, 0);
    }

#pragma unroll
    for (int mi = 0; mi < 4; ++mi) {
#pragma unroll
        for (int ni = 0; ni < 4; ++ni) {
            const long col = n0 + wn + ni * 16 + lrow;
            const long row0 = m0 + wm + mi * 16 + quad * 4;
            const void* bp;
            long bn;
            if (col < 1024)      { bp = bq; bn = col; }
            else if (col < 2048) { bp = bk; bn = col - 1024; }
            else                 { bp = bv; bn = col - 2048; }
            const float bias = fbf ? bf2f(((const ushort_t*)bp)[boff + bn])
                                   : ((const float*)bp)[boff + bn];
            if (col < 2048) {
#pragma unroll
                for (int r = 0; r < 4; ++r)
                    qk[(row0 + r) * 2048 + col] = f2bf(acc[mi][ni][r] + bias);
            } else {
                const long d = col - 2048;
                const long addr = ((row0 >> 10) << 2) * 262144 + d * 1024 + (row0 & 1023);
                ushort4 u;
                u.x = f2bf(acc[mi][ni][0] + bias);
                u.y = f2bf(acc[mi][ni][1] + bias);
                u.z = f2bf(acc[mi][ni][2] + bias);
                u.w = f2bf(acc[mi][ni][3] + bias);
                *reinterpret_cast<ushort4*>(&vT[addr]) = u;
            }
        }
    }
}

// ---------------------------------------------------------------------------
// mgemm64s: 64x64-tile split-K GEMM -> fp32 partials. BK=64. Grid (N/64, M/64, 2).
// AMODE 1: 2-partial attention combine (scales hoisted).
// AMODE 2: 4-partial attention combine (flash4 path). A = op base; streams at
//          A + k*NROW*1024, k=0..3. Ap1 unused.
// ---------------------------------------------------------------------------
template <int AMODE>
__global__ __launch_bounds__(256) void mgemm64s(
    const ushort_t* __restrict__ A, const ushort_t* __restrict__ Ap1,
    const float2* __restrict__ ml, const ushort_t* __restrict__ B,
    float* __restrict__ P, int K2, int lda, int ldb)
{
    const int z = blockIdx.z;
    const long m0 = (long)blockIdx.y * 64;
    const long n0 = (long)blockIdx.x * 64;
    const int k_beg = z * K2;
    const long OPSZ = (long)NROW * 1024;

    __shared__ __align__(16) ushort_t As[64 * 72];
    __shared__ __align__(16) ushort_t Bs[64 * 72];

    const int tid = threadIdx.x;
    const int wave = tid >> 6;
    const int lane = tid & 63;
    const int quad = lane >> 4;
    const int lrow = lane & 15;
    const int wm = (wave >> 1) * 32;
    const int wn = (wave & 1) * 32;

    const int ar = tid >> 2;          // 0..63
    const int ak = (tid & 3) << 3;    // 0,8,16,24

    float s0h[2] = {0.f, 0.f}, s1h[2] = {0.f, 0.f};
    if constexpr (AMODE == 1) {
        const long m = m0 + ar;
        const int bhbase = ((int)(m >> 10) << 2);
        const int trow = (int)(m & 1023);
        const int h0 = k_beg >> 8;
#pragma unroll
        for (int i = 0; i < 2; ++i) {
            const int bh = bhbase + h0 + i;
            const float2 v0 = ml[bh * 1024 + trow];
            const float2 v1 = ml[(16 + bh) * 1024 + trow];
            const float mm = fmaxf(v0.x, v1.x);
            const float a0 = exp2f(v0.x - mm);
            const float a1 = exp2f(v1.x - mm);
            const float inv = 1.0f / (v0.y * a0 + v1.y * a1);
            s0h[i] = a0 * inv;
            s1h[i] = a1 * inv;
        }
    }
    float sh2[2][4];
    if constexpr (AMODE == 2) {
        const long m = m0 + ar;
        const int bhbase = ((int)(m >> 10) << 2);
        const int trow = (int)(m & 1023);
        const int h0 = k_beg >> 8;
#pragma unroll
        for (int i = 0; i < 2; ++i) {
            const int bh = bhbase + h0 + i;
            float mv[4], lv[4];
#pragma unroll
            for (int k = 0; k < 4; ++k) {
                const float2 v = ml[((k << 4) + bh) * 1024 + trow];
                mv[k] = v.x; lv[k] = v.y;
            }
            const float mm = fmaxf(fmaxf(mv[0], mv[1]), fmaxf(mv[2], mv[3]));
            float den = 0.f;
            float a[4];
#pragma unroll
            for (int k = 0; k < 4; ++k) { a[k] = exp2f(mv[k] - mm); den += lv[k] * a[k]; }
            const float inv = 1.0f / den;
#pragma unroll
            for (int k = 0; k < 4; ++k) sh2[i][k] = a[k] * inv;
        }
    }

    float4v acc[2][2];
#pragma unroll
    for (int i = 0; i < 2; ++i)
#pragma unroll
        for (int j = 0; j < 2; ++j)
            acc[i][j] = (float4v){0.f, 0.f, 0.f, 0.f};

    for (int k0 = k_beg; k0 < k_beg + K2; k0 += 64) {
        __syncthreads();
#pragma unroll
        for (int p = 0; p < 2; ++p) {
            const int kc = p * 32 + ak;
            if constexpr (AMODE == 0) {
                *reinterpret_cast<short8v*>(&As[ar * 72 + kc]) =
                    *reinterpret_cast<const short8v*>(&A[(m0 + ar) * (long)lda + k0 + kc]);
            } else if constexpr (AMODE == 1) {
                const long m = m0 + ar;
                const int hh = ((k0 + kc) >> 8) - (k_beg >> 8);   // 0 or 1
                const float s0 = s0h[hh], s1 = s1h[hh];
                const ushort4 u0a = *reinterpret_cast<const ushort4*>(&A[m * 1024 + k0 + kc]);
                const ushort4 u0b = *reinterpret_cast<const ushort4*>(&A[m * 1024 + k0 + kc + 4]);
                const ushort4 u1a = *reinterpret_cast<const ushort4*>(&Ap1[m * 1024 + k0 + kc]);
                const ushort4 u1b = *reinterpret_cast<const ushort4*>(&Ap1[m * 1024 + k0 + kc + 4]);
                short8v t8;
                t8[0] = (short)f2bf(bf2f(u0a.x) * s0 + bf2f(u1a.x) * s1);
                t8[1] = (short)f2bf(bf2f(u0a.y) * s0 + bf2f(u1a.y) * s1);
                t8[2] = (short)f2bf(bf2f(u0a.z) * s0 + bf2f(u1a.z) * s1);
                t8[3] = (short)f2bf(bf2f(u0a.w) * s0 + bf2f(u1a.w) * s1);
                t8[4] = (short)f2bf(bf2f(u0b.x) * s0 + bf2f(u1b.x) * s1);
                t8[5] = (short)f2bf(bf2f(u0b.y) * s0 + bf2f(u1b.y) * s1);
                t8[6] = (short)f2bf(bf2f(u0b.z) * s0 + bf2f(u1b.z) * s1);
                t8[7] = (short)f2bf(bf2f(u0b.w) * s0 + bf2f(u1b.w) * s1);
                *reinterpret_cast<short8v*>(&As[ar * 72 + kc]) = t8;
            } else {
                const long m = m0 + ar;
                const int hh = ((k0 + kc) >> 8) - (k_beg >> 8);   // 0 or 1
                float e0 = 0.f, e1 = 0.f, e2 = 0.f, e3 = 0.f;
                float e4 = 0.f, e5 = 0.f, e6 = 0.f, e7 = 0.f;
#pragma unroll
                for (int k = 0; k < 4; ++k) {
                    const float s = sh2[hh][k];
                    const ushort4 ua = *reinterpret_cast<const ushort4*>(
                        &A[k * OPSZ + m * 1024 + k0 + kc]);
                    const ushort4 ub = *reinterpret_cast<const ushort4*>(
                        &A[k * OPSZ + m * 1024 + k0 + kc + 4]);
                    e0 += bf2f(ua.x) * s; e1 += bf2f(ua.y) * s;
                    e2 += bf2f(ua.z) * s; e3 += bf2f(ua.w) * s;
                    e4 += bf2f(ub.x) * s; e5 += bf2f(ub.y) * s;
                    e6 += bf2f(ub.z) * s; e7 += bf2f(ub.w) * s;
                }
                short8v t8;
                t8[0] = (short)f2bf(e0); t8[1] = (short)f2bf(e1);
                t8[2] = (short)f2bf(e2); t8[3] = (short)f2bf(e3);
                t8[4] = (short)f2bf(e4); t8[5] = (short)f2bf(e5);
                t8[6] = (short)f2bf(e6); t8[7] = (short)f2bf(e7);
                *reinterpret_cast<short8v*>(&As[ar * 72 + kc]) = t8;
            }
            *reinterpret_cast<short8v*>(&Bs[ar * 72 + kc]) =
                *reinterpret_cast<const short8v*>(&B[(n0 + ar) * (long)ldb + k0 + kc]);
        }
        __syncthreads();

#pragma unroll
        for (int kk = 0; kk < 2; ++kk) {
            short8v af[2], bfv[2];
#pragma unroll
            for (int i = 0; i < 2; ++i) {
                af[i]  = *reinterpret_cast<const short8v*>(
                    &As[(wm + i * 16 + lrow) * 72 + kk * 32 + quad * 8]);
                bfv[i] = *reinterpret_cast<const short8v*>(
                    &Bs[(wn + i * 16 + lrow) * 72 + kk * 32 + quad * 8]);
            }
#pragma unroll
            for (int mi = 0; mi < 2; ++mi)
#pragma unroll
                for (int ni = 0; ni < 2; ++ni)
                    acc[mi][ni] = __builtin_amdgcn_mfma_f32_16x16x32_bf16(
                        af[mi], bfv[ni], acc[mi][ni], 0, 0, 0);
        }
    }

    float* Pz = P + (long)z * NROW * CD;
#pragma unroll
    for (int mi = 0; mi < 2; ++mi)
#pragma unroll
        for (int ni = 0; ni < 2; ++ni) {
            const long col = n0 + wn + ni * 16 + lrow;
            const long row0 = m0 + wm + mi * 16 + quad * 4;
#pragma unroll
            for (int r = 0; r < 4; ++r)
                Pz[(row0 + r) * CD + col] = acc[mi][ni][r];
        }
}

// ---------------------------------------------------------------------------
// mgemm64b: 64x64-tile full-K GEMM (MLP1), BK=64, bias+relu, bf16 out.
// ---------------------------------------------------------------------------
template <int RELU>
__global__ __launch_bounds__(256) void mgemm64b(
    const ushort_t* __restrict__ A, const ushort_t* __restrict__ B,
    const void* __restrict__ bias, ushort_t* __restrict__ C,
    int K, int lda, int ldb, int ldc, long boff,
    const int* __restrict__ flagp)
{
    const long m0 = (long)blockIdx.y * 64;
    const long n0 = (long)blockIdx.x * 64;

    __shared__ __align__(16) ushort_t As[64 * 72];
    __shared__ __align__(16) ushort_t Bs[64 * 72];

    const int tid = threadIdx.x;
    const int wave = tid >> 6;
    const int lane = tid & 63;
    const int quad = lane >> 4;
    const int lrow = lane & 15;
    const int wm = (wave >> 1) * 32;
    const int wn = (wave & 1) * 32;

    const int ar = tid >> 2;
    const int ak = (tid & 3) << 3;

    float4v acc[2][2];
#pragma unroll
    for (int i = 0; i < 2; ++i)
#pragma unroll
        for (int j = 0; j < 2; ++j)
            acc[i][j] = (float4v){0.f, 0.f, 0.f, 0.f};

    for (int k0 = 0; k0 < K; k0 += 64) {
        __syncthreads();
#pragma unroll
        for (int p = 0; p < 2; ++p) {
            const int kc = p * 32 + ak;
            *reinterpret_cast<short8v*>(&As[ar * 72 + kc]) =
                *reinterpret_cast<const short8v*>(&A[(m0 + ar) * (long)lda + k0 + kc]);
            *reinterpret_cast<short8v*>(&Bs[ar * 72 + kc]) =
                *reinterpret_cast<const short8v*>(&B[(n0 + ar) * (long)ldb + k0 + kc]);
        }
        __syncthreads();

#pragma unroll
        for (int kk = 0; kk < 2; ++kk) {
            short8v af[2], bfv[2];
#pragma unroll
            for (int i = 0; i < 2; ++i) {
                af[i]  = *reinterpret_cast<const short8v*>(
                    &As[(wm + i * 16 + lrow) * 72 + kk * 32 + quad * 8]);
                bfv[i] = *reinterpret_cast<const short8v*>(
                    &Bs[(wn + i * 16 + lrow) * 72 + kk * 32 + quad * 8]);
            }
#pragma unroll
            for (int mi = 0; mi < 2; ++mi)
#pragma unroll
                for (int ni = 0; ni < 2; ++ni)
                    acc[mi][ni] = __builtin_amdgcn_mfma_f32_16x16x32_bf16(
                        af[mi], bfv[ni], acc[mi][ni], 0, 0, 0);
        }
    }

    const int fbf = *flagp;
#pragma unroll
    for (int mi = 0; mi < 2; ++mi)
#pragma unroll
        for (int ni = 0; ni < 2; ++ni) {
            const long col = n0 + wn + ni * 16 + lrow;
            const long row0 = m0 + wm + mi * 16 + quad * 4;
            const float bv = fbf ? bf2f(((const ushort_t*)bias)[boff + col])
                                 : ((const float*)bias)[boff + col];
#pragma unroll
            for (int r = 0; r < 4; ++r) {
                float v = acc[mi][ni][r] + bv;
                if (RELU) v = fmaxf(v, 0.f);
                C[(row0 + r) * (long)ldc + col] = f2bf(v);
            }
        }
}

// ---------------------------------------------------------------------------
// flash_attn2: PROVEN v7 kernel (round-1, 46.5 us). 16x16 MFMA, 32-key tiles,
// ping-pong K/V LDS, reg prefetch, setprio, S^T softmax, Ps LDS round-trip.
// 512 blocks x 256 thr, 2 blk/CU. Fallback path (small workspace).
// ---------------------------------------------------------------------------
__global__ __launch_bounds__(256) void flash_attn2(
    const ushort_t* __restrict__ qk, const ushort_t* __restrict__ vT,
    ushort_t* __restrict__ op0, ushort_t* __restrict__ op1,
    float2* __restrict__ ml)
{
    const int bx = blockIdx.x;
    const int bh = bx & 15;
    const int qt = (bx >> 4) & 15;
    const int ck = bx >> 8;
    const int b = bh >> 2, h = bh & 3;

    __shared__ __align__(16) ushort_t Ks[2][32 * 264];
    __shared__ __align__(16) ushort_t Vs[2][256 * 40];
    __shared__ __align__(16) ushort_t Ps[4][16 * 40];

    const int tid = threadIdx.x;
    const int wave = tid >> 6;
    const int lane = tid & 63;
    const int quad = lane >> 4;
    const int lrow = lane & 15;

    const long qrow0 = (long)b * CT + qt * 64;
    const int qcol = h * 256;
    const int kcol = 1024 + h * 256;
    const long vbase = (long)bh * 256 * 1024;
    const float SC = 0.0625f * LOG2E;

    short8v qf[8];
#pragma unroll
    for (int kk = 0; kk < 8; ++kk)
        qf[kk] = *reinterpret_cast<const short8v*>(
            &qk[(qrow0 + wave * 16 + lrow) * 2048 + qcol + kk * 32 + quad * 8]);

    float mrun = -1e30f, lrun = 0.f;
    float4v oacc[16];
#pragma unroll
    for (int i = 0; i < 16; ++i) oacc[i] = (float4v){0.f, 0.f, 0.f, 0.f};

    const int krow_b = tid >> 5;
    const int kcol8  = (tid & 31) * 8;
    const int vrow_b = tid >> 2;
    const int vcol8  = (tid & 3) * 8;

    short8v kreg[4], vreg[4];

    const int t_beg = ck * 512;

#pragma unroll
    for (int p = 0; p < 4; ++p) {
        kreg[p] = *reinterpret_cast<const short8v*>(
            &qk[((long)b * CT + t_beg + p * 8 + krow_b) * 2048 + kcol + kcol8]);
        vreg[p] = *reinterpret_cast<const short8v*>(
            &vT[vbase + (long)(p * 64 + vrow_b) * 1024 + t_beg + vcol8]);
    }

    for (int t0 = t_beg; t0 < t_beg + 512; t0 += 32) {
        const int bsel = (t0 >> 5) & 1;

#pragma unroll
        for (int p = 0; p < 4; ++p) {
            *reinterpret_cast<short8v*>(&Ks[bsel][(p * 8 + krow_b) * 264 + kcol8]) = kreg[p];
            *reinterpret_cast<short8v*>(&Vs[bsel][(p * 64 + vrow_b) * 40 + vcol8]) = vreg[p];
        }

        if (t0 + 32 < t_beg + 512) {
            const int tn = t0 + 32;
#pragma unroll
            for (int p = 0; p < 4; ++p) {
                kreg[p] = *reinterpret_cast<const short8v*>(
                    &qk[((long)b * CT + tn + p * 8 + krow_b) * 2048 + kcol + kcol8]);
                vreg[p] = *reinterpret_cast<const short8v*>(
                    &vT[vbase + (long)(p * 64 + vrow_b) * 1024 + tn + vcol8]);
            }
        }

        __syncthreads();

        float4v sacc[2];
        sacc[0] = (float4v){0.f, 0.f, 0.f, 0.f};
        sacc[1] = (float4v){0.f, 0.f, 0.f, 0.f};
        __builtin_amdgcn_s_setprio(1);
#pragma unroll
        for (int kk = 0; kk < 8; ++kk) {
#pragma unroll
            for (int ni = 0; ni < 2; ++ni) {
                short8v bk = *reinterpret_cast<const short8v*>(
                    &Ks[bsel][(ni * 16 + lrow) * 264 + kk * 32 + quad * 8]);
                sacc[ni] = __builtin_amdgcn_mfma_f32_16x16x32_bf16(
                    bk, qf[kk], sacc[ni], 0, 0, 0);   // swapped -> S^T
            }
        }
        __builtin_amdgcn_s_setprio(0);
#pragma unroll
        for (int ni = 0; ni < 2; ++ni)
#pragma unroll
            for (int r = 0; r < 4; ++r)
                sacc[ni][r] *= SC;

        float mx = fmaxf(fmaxf(fmaxf(sacc[0][0], sacc[0][1]),
                               fmaxf(sacc[0][2], sacc[0][3])),
                         fmaxf(fmaxf(sacc[1][0], sacc[1][1]),
                               fmaxf(sacc[1][2], sacc[1][3])));
        mx = fmaxf(mx, __shfl_xor(mx, 16));
        mx = fmaxf(mx, __shfl_xor(mx, 32));

        if (__ballot(mx > mrun + 1.0f) != 0ull) {
            const float mnew = fmaxf(mrun, mx);
            const float alpha = exp2f(mrun - mnew);
            mrun = mnew;
            lrun *= alpha;
            float a4[4];
#pragma unroll
            for (int r = 0; r < 4; ++r)
                a4[r] = __shfl(alpha, quad * 4 + r);
#pragma unroll
            for (int ni = 0; ni < 16; ++ni)
#pragma unroll
                for (int r = 0; r < 4; ++r)
                    oacc[ni][r] *= a4[r];
        }

        float s = 0.f;
#pragma unroll
        for (int ni = 0; ni < 2; ++ni) {
            ushort4 pu;
#pragma unroll
            for (int r = 0; r < 4; ++r) {
                const float pv = exp2f(sacc[ni][r] - mrun);
                s += pv;
                (&pu.x)[r] = f2bf(pv);
            }
            *reinterpret_cast<ushort4*>(
                &Ps[wave][lrow * 40 + ni * 16 + quad * 4]) = pu;
        }
        s += __shfl_xor(s, 16);
        s += __shfl_xor(s, 32);
        lrun += s;

        {
            short8v ap = *reinterpret_cast<const short8v*>(
                &Ps[wave][lrow * 40 + quad * 8]);
            __builtin_amdgcn_s_setprio(1);
#pragma unroll
            for (int ni = 0; ni < 16; ++ni) {
                short8v bv = *reinterpret_cast<const short8v*>(
                    &Vs[bsel][(ni * 16 + lrow) * 40 + quad * 8]);
                oacc[ni] = __builtin_amdgcn_mfma_f32_16x16x32_bf16(
                    ap, bv, oacc[ni], 0, 0, 0);
            }
            __builtin_amdgcn_s_setprio(0);
        }
    }

    if (quad == 0)
        ml[((ck << 4) + bh) * 1024 + qt * 64 + wave * 16 + lrow] =
            make_float2(mrun, lrun);

    ushort_t* op = ck ? op1 : op0;
#pragma unroll
    for (int ni = 0; ni < 16; ++ni)
#pragma unroll
        for (int r = 0; r < 4; ++r)
            op[(qrow0 + wave * 16 + quad * 4 + r) * 1024 + (h << 8) + ni * 16 + lrow]
                = f2bf(oacc[ni][r]);
}

// ---------------------------------------------------------------------------
// flash_attn4: v8 32x32 kernel (proven correct r3, 240 VGPR, no spill) with
// 4-way key split for 2 blocks/CU. Grid 512 = 16 bh x 8 qg x 4 ck; each block
// = 4 waves x 32 q-rows (128 rows) x 256 keys. LDS 72 KB -> 2 blk/CU = 8
// waves/CU = 2 waves/SIMD (v8's only deficit was 1 blk/CU occupancy; per-wave
// it was 1.26x the 16x16 kernel). Partials: op[ck] (4 buffers) + ml[4][16].
// ---------------------------------------------------------------------------
__global__ __launch_bounds__(256, 1) void flash_attn4(
    const ushort_t* __restrict__ qk, const ushort_t* __restrict__ vT,
    ushort_t* __restrict__ opb, float2* __restrict__ ml)
{
    const int bx = blockIdx.x;
    const int bh = bx & 15;           // b*4 + h
    const int qg = (bx >> 4) & 7;     // 128-row q-group
    const int ck = bx >> 7;           // key-chunk 0..3 (256 keys each)
    const int bb = bh >> 2, h = bh & 3;

    __shared__ __align__(16) ushort_t Ks[2][32 * 256];   // swizzled [t][d]
    __shared__ __align__(16) ushort_t Vs[2][256 * 40];   // padded  [d][t]

    const int tid = threadIdx.x;
    const int wave = tid >> 6;
    const int lane = tid & 63;
    const int col = lane & 31;
    const int hi = lane >> 5;
    const int hi8 = hi << 3;

    const long qrow0w = (long)bb * CT + qg * 128 + wave * 32;
    const int qcol = h * 256;
    const int kcol = 1024 + h * 256;
    const long vbase = (long)bh * 256 * 1024;
    const float SC = 0.0625f * LOG2E;
    const int t_beg = ck * 256;

    const int kr_ = tid >> 5;          // 0..7
    const int kc_ = (tid & 31) << 3;   // 0..248
    const int vr_ = tid >> 2;          // 0..63
    const int vc_ = (tid & 3) << 3;    // 0..24

    short8v kreg[4], vreg[4];
#pragma unroll
    for (int i = 0; i < 4; ++i) {
        kreg[i] = *reinterpret_cast<const short8v*>(
            &qk[((long)bb * CT + t_beg + i * 8 + kr_) * 2048 + kcol + kc_]);
        vreg[i] = *reinterpret_cast<const short8v*>(
            &vT[vbase + (long)(i * 64 + vr_) * 1024 + t_beg + vc_]);
    }

    short8v qf[16];
#pragma unroll
    for (int s = 0; s < 16; ++s)
        qf[s] = *reinterpret_cast<const short8v*>(
            &qk[(qrow0w + col) * 2048 + qcol + s * 16 + hi8]);

    float mrun = -1e30f, lrun = 0.f;
    float16v oacc[8];
#pragma unroll
    for (int i = 0; i < 8; ++i)
#pragma unroll
        for (int j = 0; j < 16; ++j) oacc[i][j] = 0.f;

    // stage tile 0 (K swizzled: phys 16B-chunk = logical chunk ^ row)
#pragma unroll
    for (int i = 0; i < 4; ++i) {
        const int kr = i * 8 + kr_;
        *reinterpret_cast<short8v*>(
            &Ks[0][kr * 256 + (((tid & 31) ^ kr) << 3)]) = kreg[i];
        *reinterpret_cast<short8v*>(
            &Vs[0][(i * 64 + vr_) * 40 + vc_]) = vreg[i];
    }
    __syncthreads();

    const int krowbase = col * 256;
    const int kxor = col << 4;

    for (int it = 0; it < 8; ++it) {
        const int cur = it & 1;

        if (it < 7) {
            const int tn = t_beg + (it + 1) * 32;
#pragma unroll
            for (int i = 0; i < 4; ++i) {
                kreg[i] = *reinterpret_cast<const short8v*>(
                    &qk[((long)bb * CT + tn + i * 8 + kr_) * 2048 + kcol + kc_]);
                vreg[i] = *reinterpret_cast<const short8v*>(
                    &vT[vbase + (long)(i * 64 + vr_) * 1024 + tn + vc_]);
            }
        }

        // ---- QK^T -> S^T[t][q]
        float16v sa, sb;
#pragma unroll
        for (int j = 0; j < 16; ++j) { sa[j] = 0.f; sb[j] = 0.f; }
        __builtin_amdgcn_s_setprio(1);
#pragma unroll
        for (int s = 0; s < 16; s += 2) {
            const int o0 = ((s * 32 + hi * 16) ^ kxor) >> 1;
            const int o1 = (((s + 1) * 32 + hi * 16) ^ kxor) >> 1;
            const short8v k0 = *reinterpret_cast<const short8v*>(&Ks[cur][krowbase + o0]);
            const short8v k1 = *reinterpret_cast<const short8v*>(&Ks[cur][krowbase + o1]);
            sa = __builtin_amdgcn_mfma_f32_32x32x16_bf16(k0, qf[s], sa, 0, 0, 0);
            sb = __builtin_amdgcn_mfma_f32_32x32x16_bf16(k1, qf[s + 1], sb, 0, 0, 0);
        }
        __builtin_amdgcn_s_setprio(0);

        float sv[16];
#pragma unroll
        for (int j = 0; j < 16; ++j) sv[j] = (sa[j] + sb[j]) * SC;

        float mx = sv[0];
#pragma unroll
        for (int j = 1; j < 16; ++j) mx = fmaxf(mx, sv[j]);
        mx = fmaxf(mx, __shfl_xor(mx, 32));

        if (__ballot(mx > mrun + 1.0f) != 0ull) {
            const float mnew = fmaxf(mrun, mx);
            const float alpha = exp2f(mrun - mnew);
            mrun = mnew;
            lrun *= alpha;
            float ar[16];
#pragma unroll
            for (int r = 0; r < 16; ++r)
                ar[r] = __shfl(alpha, (r & 3) + 8 * (r >> 2) + (hi << 2));
#pragma unroll
            for (int dt = 0; dt < 8; ++dt)
#pragma unroll
                for (int r = 0; r < 16; ++r)
                    oacc[dt][r] *= ar[r];
        }

        float p[16];
        float s = 0.f;
#pragma unroll
        for (int j = 0; j < 16; ++j) { p[j] = exp2f(sv[j] - mrun); s += p[j]; }
        s += __shfl_xor(s, 32);
        lrun += s;

        // ---- pack P to bf16 PV A-frags (half-exchange via shfl_xor 32)
        const unsigned c01 = (unsigned)f2bf(p[0])  | ((unsigned)f2bf(p[1])  << 16);
        const unsigned c23 = (unsigned)f2bf(p[2])  | ((unsigned)f2bf(p[3])  << 16);
        const unsigned c45 = (unsigned)f2bf(p[4])  | ((unsigned)f2bf(p[5])  << 16);
        const unsigned c67 = (unsigned)f2bf(p[6])  | ((unsigned)f2bf(p[7])  << 16);
        const unsigned d01 = (unsigned)f2bf(p[8])  | ((unsigned)f2bf(p[9])  << 16);
        const unsigned d23 = (unsigned)f2bf(p[10]) | ((unsigned)f2bf(p[11]) << 16);
        const unsigned d45 = (unsigned)f2bf(p[12]) | ((unsigned)f2bf(p[13]) << 16);
        const unsigned d67 = (unsigned)f2bf(p[14]) | ((unsigned)f2bf(p[15]) << 16);
        const unsigned x01 = __shfl_xor(c01, 32);
        const unsigned x23 = __shfl_xor(c23, 32);
        const unsigned x45 = __shfl_xor(c45, 32);
        const unsigned x67 = __shfl_xor(c67, 32);
        const unsigned y01 = __shfl_xor(d01, 32);
        const unsigned y23 = __shfl_xor(d23, 32);
        const unsigned y45 = __shfl_xor(d45, 32);
        const unsigned y67 = __shfl_xor(d67, 32);
        union { unsigned u[4]; short8v v; } pf0, pf1;
        pf0.u[0] = hi ? x45 : c01;
        pf0.u[1] = hi ? x67 : c23;
        pf0.u[2] = hi ? c45 : x01;
        pf0.u[3] = hi ? c67 : x23;
        pf1.u[0] = hi ? y45 : d01;
        pf1.u[1] = hi ? y67 : d23;
        pf1.u[2] = hi ? d45 : y01;
        pf1.u[3] = hi ? d67 : y23;

        // ---- PV
        __builtin_amdgcn_s_setprio(1);
#pragma unroll
        for (int dt = 0; dt < 8; ++dt) {
            const int vb = (dt * 32 + col) * 40 + hi8;
            const short8v v0 = *reinterpret_cast<const short8v*>(&Vs[cur][vb]);
            const short8v v1 = *reinterpret_cast<const short8v*>(&Vs[cur][vb + 16]);
            oacc[dt] = __builtin_amdgcn_mfma_f32_32x32x16_bf16(pf0.v, v0, oacc[dt], 0, 0, 0);
            oacc[dt] = __builtin_amdgcn_mfma_f32_32x32x16_bf16(pf1.v, v1, oacc[dt], 0, 0, 0);
        }
        __builtin_amdgcn_s_setprio(0);

        if (it < 7) {
            const int nb = cur ^ 1;
#pragma unroll
            for (int i = 0; i < 4; ++i) {
                const int kr = i * 8 + kr_;
                *reinterpret_cast<short8v*>(
                    &Ks[nb][kr * 256 + (((tid & 31) ^ kr) << 3)]) = kreg[i];
                *reinterpret_cast<short8v*>(
                    &Vs[nb][(i * 64 + vr_) * 40 + vc_]) = vreg[i];
            }
            __syncthreads();
        }
    }

    // ---- epilogue: ml + unnormalized O partial (combined by mgemm64s<2>)
    if (lane < 32) {
        const int trow = (int)((qrow0w + lane) & 1023);
        ml[((ck << 4) + bh) * 1024 + trow] = make_float2(mrun, lrun);
    }
    ushort_t* op = opb + (long)ck * ((long)NROW * 1024);
#pragma unroll
    for (int dt = 0; dt < 8; ++dt)
#pragma unroll
        for (int r = 0; r < 16; ++r) {
            const int row = (r & 3) + 8 * (r >> 2) + (hi << 2);
            op[(qrow0w + row) * 1024 + (h << 8) + dt * 32 + col] = f2bf(oacc[dt][r]);
        }
}

// ---------------------------------------------------------------------------
// ln_p: x = P0[row]+P1[row] + gbias + res; y = LN(x)*s + b.
// FINAL=1 writes d_out in flag dtype.
// ---------------------------------------------------------------------------
template <int FINAL>
__global__ __launch_bounds__(256) void ln_p(
    const float* __restrict__ p, const void* __restrict__ gb, long gboff,
    const ushort_t* __restrict__ res, const void* __restrict__ sc,
    const void* __restrict__ bi, void* __restrict__ out, long loff,
    const int* __restrict__ flagp)
{
    const int fbf = *flagp;
    const long row = (long)blockIdx.x * CD;
    const int t = threadIdx.x;
    const float gbv = fbf ? bf2f(((const ushort_t*)gb)[gboff + t])
                          : ((const float*)gb)[gboff + t];
    const float x = p[row + t] + p[(long)NROW * CD + row + t] + gbv + bf2f(res[row + t]);

    __shared__ float r1[256];
    __shared__ float r2[256];
    r1[t] = x;
    r2[t] = x * x;
    __syncthreads();
    for (int s = 128; s > 0; s >>= 1) {
        if (t < s) { r1[t] += r1[t + s]; r2[t] += r2[t + s]; }
        __syncthreads();
    }
    const float mean = r1[0] * (1.0f / CD);
    const float var = r2[0] * (1.0f / CD) - mean * mean;
    const float rstd = rsqrtf(var + 1e-5f);
    const float s_v = fbf ? bf2f(((const ushort_t*)sc)[loff + t]) : ((const float*)sc)[loff + t];
    const float b_v = fbf ? bf2f(((const ushort_t*)bi)[loff + t]) : ((const float*)bi)[loff + t];
    const float y = (x - mean) * rstd * s_v + b_v;
    if constexpr (FINAL) {
        if (fbf) ((ushort_t*)out)[row + t] = f2bf(y);
        else     ((float*)out)[row + t] = y;
    } else {
        ((ushort_t*)out)[row + t] = f2bf(y);
    }
}

__global__ __launch_bounds__(256) void in_convert(
    const void* __restrict__ in, ushort_t* __restrict__ x,
    const int* __restrict__ flagp)
{
    const int fbf = *flagp;
    const long i = ((long)blockIdx.x * 256 + threadIdx.x) << 2;
    if (fbf) {
        *reinterpret_cast<ushort4*>(x + i) =
            *reinterpret_cast<const ushort4*>((const ushort_t*)in + i);
    } else {
        float4 f = *reinterpret_cast<const float4*>((const float*)in + i);
        ushort4 u;
        u.x = f2bf(f.x); u.y = f2bf(f.y); u.z = f2bf(f.z); u.w = f2bf(f.w);
        *reinterpret_cast<ushort4*>(x + i) = u;
    }
}

// ---------------------------------------------------------------------------
// Orchestration. Big-ws path (>=64 MiB): flash4 + 4-partial combine, 63.5 MiB.
// Small-ws fallback: round-1 layout/configuration verbatim (47.25 MiB).
// ---------------------------------------------------------------------------
extern "C" void kernel_launch(void* const* d_in, const int* in_sizes, int n_in,
                              void* d_out, int out_size, void* d_ws, size_t ws_size,
                              hipStream_t stream)
{
    const void* queries = d_in[0];
    const void* Wq = d_in[1];  const void* bq = d_in[2];
    const void* Wk = d_in[3];  const void* bk = d_in[4];
    const void* Wv = d_in[5];  const void* bv = d_in[6];
    const void* Wo = d_in[7];  const void* bo = d_in[8];
    const void* ln1s = d_in[9];  const void* ln1b = d_in[10];
    const void* W1 = d_in[11]; const void* b1 = d_in[12];
    const void* W2 = d_in[13]; const void* b2 = d_in[14];
    const void* ln2s = d_in[15]; const void* ln2b = d_in[16];

    const bool big = ws_size >= 67108864ULL;   // 64 MiB

    char* p = (char*)d_ws;
    int* flagp = (int*)p;             p += 256;
    ushort_t* wqkvT = (ushort_t*)p;   p += (long)CL * 3072 * 256 * 2;  // 3 MiB
    ushort_t* w1T   = (ushort_t*)p;   p += (long)CL * 1024 * 256 * 2;  // 1 MiB
    ushort_t* wscr  = (ushort_t*)p;   p += (long)2 * 256 * 1024 * 2;   // 1 MiB
    ushort_t* xa    = (ushort_t*)p;   p += (long)NROW * CD * 2;        // 2 MiB
    ushort_t* qk    = (ushort_t*)p;   p += (long)NROW * 2048 * 2;      // 16 MiB
    ushort_t* vT    = (ushort_t*)p;   p += (long)16 * 256 * 1024 * 2;  // 8 MiB
    ushort_t* opb   = (ushort_t*)p;
    if (big) p += (long)4 * NROW * 1024 * 2;   // 32 MiB (op0..op3)
    else     p += (long)2 * NROW * 1024 * 2;   // 16 MiB (op0, op1)
    float2*   ml    = (float2*)p;
    if (big) p += (long)4 * 16 * 1024 * 8;     // 0.5 MiB
    else     p += (long)2 * 16 * 1024 * 8;     // 0.25 MiB
    ushort_t* op0   = opb;
    ushort_t* op1   = opb + (long)NROW * 1024;
    ushort_t* h     = vT;             // MLP hidden reuses vT
    float*    pgem  = (float*)qk;     // fp32 partials reuse qk (dead post-flash)

    detect_kernel<<<1, 256, 0, stream>>>((const ushort_t*)Wq, 2048, flagp);
    tconv_all<<<dim3(32, 8, 8), 256, 0, stream>>>(
        Wq, Wk, Wv, W1, wqkvT, w1T, flagp);
    in_convert<<<(NROW * CD) / 1024, 256, 0, stream>>>(queries, xa, flagp);

    for (int l = 0; l < CL; ++l) {
        // 1) merged QKV projection + Wo/W2 transpose (one dispatch)
        qkv_tconv<<<dim3(1280, 1, 1), 256, 0, stream>>>(
            xa, wqkvT + (long)l * 3072 * 256, bq, bk, bv, qk, vT,
            Wo, W2, wscr, (long)l * 1024, (long)l * 1024 * 256, flagp);
        // 2)+3) flash attention + O projection w/ fused partial-combine
        if (big) {
            flash_attn4<<<512, 256, 0, stream>>>(qk, vT, opb, ml);
            mgemm64s<2><<<dim3(4, 64, 2), 256, 0, stream>>>(
                opb, nullptr, ml, wscr, pgem, 512, 1024, 1024);
        } else {
            flash_attn2<<<512, 256, 0, stream>>>(qk, vT, op0, op1, ml);
            mgemm64s<1><<<dim3(4, 64, 2), 256, 0, stream>>>(
                op0, op1, ml, wscr, pgem, 512, 1024, 1024);
        }
        // 4) xa = LN(pgem0+pgem1 + bo + xa)
        ln_p<0><<<NROW, 256, 0, stream>>>(pgem, bo, (long)l * 256, xa,
                                          ln1s, ln1b, xa, (long)l * 256, flagp);
        // 5) h = relu(xa @ w1T^T + b1)  (BK=64)
        mgemm64b<1><<<dim3(16, 64, 1), 256, 0, stream>>>(
            xa, w1T + (long)l * 1024 * 256, b1, h,
            256, 256, 256, 1024, (long)l * 1024, flagp);
        // 6) MLP2 -> fp32 pgem  (BK=64)
        mgemm64s<0><<<dim3(4, 64, 2), 256, 0, stream>>>(
            h, nullptr, nullptr, wscr + 262144, pgem, 512, 1024, 1024);
        // 7) LN(pgem0+pgem1 + b2 + xa): final layer writes d_out directly
        if (l == CL - 1)
            ln_p<1><<<NROW, 256, 0, stream>>>(pgem, b2, (long)l * 256, xa,
                                              ln2s, ln2b, d_out, (long)l * 256, flagp);
        else
            ln_p<0><<<NROW, 256, 0, stream>>>(pgem, b2, (long)l * 256, xa,
                                              ln2s, ln2b, xa, (long)l * 256, flagp);
    }
}